// Round 2
// baseline (1194.525 us; speedup 1.0000x reference)
//
#include <hip/hip_runtime.h>

typedef _Float16 half_t;
typedef _Float16 half8  __attribute__((ext_vector_type(8)));
typedef _Float16 half4v __attribute__((ext_vector_type(4)));
typedef float    f32x4  __attribute__((ext_vector_type(4)));

#define AS1 __attribute__((address_space(1)))
#define AS3 __attribute__((address_space(3)))

#define MODE_H16  0   // store fp16
#define MODE_F32R 1   // store fp32 = acc + bias + residual
#define MODE_GELU 2   // store fp16 = gelu(acc + bias)

__device__ __forceinline__ f32x4 zero4() {
    f32x4 z; z[0] = 0.f; z[1] = 0.f; z[2] = 0.f; z[3] = 0.f; return z;
}

__device__ __forceinline__ half8 lds_frag(const half_t* p) {
    union { uint4 u; half8 h; } c;
    c.u = *(const uint4*)p;
    return c.h;
}

// async global->LDS, 16B/lane; LDS dest is wave-uniform base + lane*16
__device__ __forceinline__ void gl_lds16(const half_t* g, half_t* l) {
    __builtin_amdgcn_global_load_lds(
        (AS1 unsigned int*)(unsigned long long)(const void*)g,
        (AS3 unsigned int*)l,
        16, 0, 0);
}

// ---------------------------------------------------------------------------
// C[M,N] = A[M,K] @ Bt[N,K]^T + bias, fused epilogues. 128x128 tile, BK=32.
// ---------------------------------------------------------------------------
__global__ __launch_bounds__(256) void gemm_bt(
    const half_t* __restrict__ A,
    const half_t* __restrict__ Bt,
    const float*  __restrict__ bias,
    const float*  __restrict__ res,
    void* __restrict__ out,
    int M, int N, int K, int mode)
{
    __shared__ __align__(16) half_t As[128 * 32];
    __shared__ __align__(16) half_t Bs[128 * 32];

    const int tid  = threadIdx.x;
    const int w    = tid >> 6, lane = tid & 63;
    const int m0   = blockIdx.y * 128, n0 = blockIdx.x * 128;
    const int lr   = lane >> 2;        // 0..15
    const int lc   = (lane & 3) * 8;   // k offset within BK
    const int g    = lane >> 4, ml = lane & 15;
    const int mo   = (w >> 1) * 64, no = (w & 1) * 64;

    f32x4 acc[4][4];
#pragma unroll
    for (int i = 0; i < 4; i++)
#pragma unroll
        for (int j = 0; j < 4; j++) acc[i][j] = zero4();

    const half_t* Ag = A  + (size_t)m0 * K;
    const half_t* Bg = Bt + (size_t)n0 * K;

    for (int k0 = 0; k0 < K; k0 += 32) {
        __syncthreads();
#pragma unroll
        for (int i = 0; i < 2; i++) {
            int r = (w * 2 + i) * 16 + lr;
            gl_lds16(Ag + (size_t)r * K + k0 + lc, &As[(w * 2 + i) * 512]);
            gl_lds16(Bg + (size_t)r * K + k0 + lc, &Bs[(w * 2 + i) * 512]);
        }
        __syncthreads();

        half8 af[4], bf[4];
#pragma unroll
        for (int i = 0; i < 4; i++) af[i] = lds_frag(&As[(mo + i * 16 + ml) * 32 + g * 8]);
#pragma unroll
        for (int j = 0; j < 4; j++) bf[j] = lds_frag(&Bs[(no + j * 16 + ml) * 32 + g * 8]);
#pragma unroll
        for (int i = 0; i < 4; i++)
#pragma unroll
            for (int j = 0; j < 4; j++)
                acc[i][j] = __builtin_amdgcn_mfma_f32_16x16x32_f16(af[i], bf[j], acc[i][j], 0, 0, 0);
    }

    const int gm0 = m0 + mo, gn0 = n0 + no;
#pragma unroll
    for (int j = 0; j < 4; j++) {
        int col = gn0 + j * 16 + ml;
        float bv = bias[col];
#pragma unroll
        for (int i = 0; i < 4; i++) {
#pragma unroll
            for (int r = 0; r < 4; r++) {
                int row = gm0 + i * 16 + g * 4 + r;
                float v = acc[i][j][r] + bv;
                size_t idx = (size_t)row * N + col;
                if (mode == MODE_F32R) {
                    ((float*)out)[idx] = v + res[idx];
                } else if (mode == MODE_GELU) {
                    v = 0.5f * v * (1.f + erff(v * 0.70710678118654752f));
                    ((half_t*)out)[idx] = (half_t)v;
                } else {
                    ((half_t*)out)[idx] = (half_t)v;
                }
            }
        }
    }
}

// ---------------------------------------------------------------------------
// 128x64-tile GEMM for N=1024 cases (2 blocks/CU instead of 1). MODE_F32R.
// ---------------------------------------------------------------------------
__global__ __launch_bounds__(256) void gemm_bt64(
    const half_t* __restrict__ A,
    const half_t* __restrict__ Bt,
    const float*  __restrict__ bias,
    const float*  __restrict__ res,
    float* __restrict__ out,
    int M, int N, int K)
{
    __shared__ __align__(16) half_t As[128 * 32];
    __shared__ __align__(16) half_t Bs[64 * 32];

    const int tid  = threadIdx.x;
    const int w    = tid >> 6, lane = tid & 63;
    const int m0   = blockIdx.y * 128, n0 = blockIdx.x * 64;
    const int lr   = lane >> 2, lc = (lane & 3) * 8;
    const int g    = lane >> 4, ml = lane & 15;
    const int mo   = w * 32;

    f32x4 acc[2][4];
#pragma unroll
    for (int i = 0; i < 2; i++)
#pragma unroll
        for (int j = 0; j < 4; j++) acc[i][j] = zero4();

    const half_t* Ag = A  + (size_t)m0 * K;
    const half_t* Bg = Bt + (size_t)n0 * K;

    for (int k0 = 0; k0 < K; k0 += 32) {
        __syncthreads();
#pragma unroll
        for (int i = 0; i < 2; i++)
            gl_lds16(Ag + (size_t)((w * 2 + i) * 16 + lr) * K + k0 + lc, &As[(w * 2 + i) * 512]);
        gl_lds16(Bg + (size_t)(w * 16 + lr) * K + k0 + lc, &Bs[w * 512]);
        __syncthreads();

        half8 af[2], bf[4];
#pragma unroll
        for (int i = 0; i < 2; i++) af[i] = lds_frag(&As[(mo + i * 16 + ml) * 32 + g * 8]);
#pragma unroll
        for (int j = 0; j < 4; j++) bf[j] = lds_frag(&Bs[(j * 16 + ml) * 32 + g * 8]);
#pragma unroll
        for (int i = 0; i < 2; i++)
#pragma unroll
            for (int j = 0; j < 4; j++)
                acc[i][j] = __builtin_amdgcn_mfma_f32_16x16x32_f16(af[i], bf[j], acc[i][j], 0, 0, 0);
    }

    const int gm0 = m0 + mo;
#pragma unroll
    for (int j = 0; j < 4; j++) {
        int col = n0 + j * 16 + ml;
        float bv = bias[col];
#pragma unroll
        for (int i = 0; i < 2; i++) {
#pragma unroll
            for (int r = 0; r < 4; r++) {
                int row = gm0 + i * 16 + g * 4 + r;
                size_t idx = (size_t)row * N + col;
                out[idx] = acc[i][j][r] + bv + res[idx];
            }
        }
    }
}

// ---------------------------------------------------------------------------
// Fused QKV GEMM: N=3072 (Wq|Wk|Wv transposed, per-layer contiguous).
// cols [0,1024) -> Q fp16, [1024,2048) -> K fp16, [2048,3072) -> V^T fp16.
// ---------------------------------------------------------------------------
__global__ __launch_bounds__(256) void gemm_qkv(
    const half_t* __restrict__ A,
    const half_t* __restrict__ Bt,
    const float*  __restrict__ bq,
    const float*  __restrict__ bk,
    const float*  __restrict__ bv,
    half_t* __restrict__ Qo, half_t* __restrict__ Ko, half_t* __restrict__ Vto,
    int M, int K)
{
    __shared__ __align__(16) half_t As[128 * 32];
    __shared__ __align__(16) half_t Bs[128 * 32];

    const int tid  = threadIdx.x;
    const int w    = tid >> 6, lane = tid & 63;
    const int m0   = blockIdx.y * 128, n0 = blockIdx.x * 128;
    const int lr   = lane >> 2, lc = (lane & 3) * 8;
    const int g    = lane >> 4, ml = lane & 15;
    const int mo   = (w >> 1) * 64, no = (w & 1) * 64;

    f32x4 acc[4][4];
#pragma unroll
    for (int i = 0; i < 4; i++)
#pragma unroll
        for (int j = 0; j < 4; j++) acc[i][j] = zero4();

    const half_t* Ag = A  + (size_t)m0 * K;
    const half_t* Bg = Bt + (size_t)n0 * K;

    for (int k0 = 0; k0 < K; k0 += 32) {
        __syncthreads();
#pragma unroll
        for (int i = 0; i < 2; i++) {
            int r = (w * 2 + i) * 16 + lr;
            gl_lds16(Ag + (size_t)r * K + k0 + lc, &As[(w * 2 + i) * 512]);
            gl_lds16(Bg + (size_t)r * K + k0 + lc, &Bs[(w * 2 + i) * 512]);
        }
        __syncthreads();

        half8 af[4], bf[4];
#pragma unroll
        for (int i = 0; i < 4; i++) af[i] = lds_frag(&As[(mo + i * 16 + ml) * 32 + g * 8]);
#pragma unroll
        for (int j = 0; j < 4; j++) bf[j] = lds_frag(&Bs[(no + j * 16 + ml) * 32 + g * 8]);
#pragma unroll
        for (int i = 0; i < 4; i++)
#pragma unroll
            for (int j = 0; j < 4; j++)
                acc[i][j] = __builtin_amdgcn_mfma_f32_16x16x32_f16(af[i], bf[j], acc[i][j], 0, 0, 0);
    }

    const int seg  = n0 >> 10;                  // block-uniform: 0=Q,1=K,2=V
    const int nloc = (n0 & 1023) + no;
    const float* bias = (seg == 0) ? bq : (seg == 1) ? bk : bv;
    const int gm0 = m0 + mo;

    if (seg < 2) {
        half_t* O = (seg == 0) ? Qo : Ko;
#pragma unroll
        for (int j = 0; j < 4; j++) {
            int col = nloc + j * 16 + ml;
            float bvv = bias[col];
#pragma unroll
            for (int i = 0; i < 4; i++)
#pragma unroll
                for (int r = 0; r < 4; r++)
                    O[(size_t)(gm0 + i * 16 + g * 4 + r) * 1024 + col] =
                        (half_t)(acc[i][j][r] + bvv);
        }
    } else {
#pragma unroll
        for (int j = 0; j < 4; j++) {
            int col = nloc + j * 16 + ml;
            float bvv = bias[col];
#pragma unroll
            for (int i = 0; i < 4; i++) {
                int rowb = gm0 + i * 16 + g * 4;
                int bb = rowb >> 11, sl = rowb & 2047;       // S=2048
                half4v v;
#pragma unroll
                for (int r = 0; r < 4; r++) v[r] = (half_t)(acc[i][j][r] + bvv);
                *(half4v*)&Vto[((size_t)bb * 1024 + col) * 2048 + sl] = v;
            }
        }
    }
}

// ---------------------------------------------------------------------------
// Flash attention, S^T formulation, no barriers, no K/V LDS staging.
// Q,K: [B*S][H] fp16 ; Vt: [B][H][S] fp16 ; ctx: [B*S][H] fp16.
// Per block: 64 q (4 waves x 16), loop kv in tiles of 64.
// ---------------------------------------------------------------------------
__global__ __launch_bounds__(256) void flash_attn(
    const half_t* __restrict__ Q,
    const half_t* __restrict__ Kq,
    const half_t* __restrict__ Vt,
    const float*  __restrict__ mask,   // [B*S] additive
    half_t* __restrict__ ctx,
    int S, int H)
{
    __shared__ __align__(16) half_t Ps[4 * 16 * 72];   // per-wave P[q=16][kv=64], stride 72

    const int qt = blockIdx.x, h = blockIdx.y, b = blockIdx.z;
    const int tid = threadIdx.x, w = tid >> 6, lane = tid & 63;
    const int g = lane >> 4, ml = lane & 15;

    const half_t* Qg = Q  + ((size_t)(b * S + qt * 64 + w * 16)) * H + h * 64;
    const half_t* Kg = Kq + ((size_t)(b * S)) * H + h * 64;
    const half_t* Vg = Vt + ((size_t)b * H + h * 64) * (size_t)S;
    const float*  mk = mask + (size_t)b * S;

    // Q fragment (B-operand): B[n=q=ml][k=g*8+j]
    const half8 qf0 = *(const half8*)(Qg + (size_t)ml * H + g * 8);
    const half8 qf1 = *(const half8*)(Qg + (size_t)ml * H + 32 + g * 8);

    float mrow = -1e30f, lrow = 0.f;   // softmax state for q = ml
    f32x4 o[4];
#pragma unroll
    for (int jd = 0; jd < 4; jd++) o[jd] = zero4();
    half_t* Pw = &Ps[w * 16 * 72];

    for (int kv0 = 0; kv0 < S; kv0 += 64) {
        // S^T tiles: mfma(K_frag, Q_frag) -> row = kv-local = g*4+r, col = q = ml
        f32x4 s[4];
#pragma unroll
        for (int jt = 0; jt < 4; jt++) {
            const half_t* kr = Kg + (size_t)(kv0 + jt * 16 + ml) * H;
            half8 kf0 = *(const half8*)(kr + g * 8);
            half8 kf1 = *(const half8*)(kr + 32 + g * 8);
            s[jt] = __builtin_amdgcn_mfma_f32_16x16x32_f16(kf0, qf0, zero4(), 0, 0, 0);
            s[jt] = __builtin_amdgcn_mfma_f32_16x16x32_f16(kf1, qf1, s[jt],   0, 0, 0);
        }
#pragma unroll
        for (int jt = 0; jt < 4; jt++) {
            float4 mv = *(const float4*)(mk + kv0 + jt * 16 + g * 4);
            s[jt][0] = s[jt][0] * 0.125f + mv.x;
            s[jt][1] = s[jt][1] * 0.125f + mv.y;
            s[jt][2] = s[jt][2] * 0.125f + mv.z;
            s[jt][3] = s[jt][3] * 0.125f + mv.w;
        }
        // row max for q=ml: 16 in-register values + reduce across g (xor 16,32)
        float mx = -1e30f;
#pragma unroll
        for (int jt = 0; jt < 4; jt++)
#pragma unroll
            for (int r = 0; r < 4; r++) mx = fmaxf(mx, s[jt][r]);
        mx = fmaxf(mx, __shfl_xor(mx, 16));
        mx = fmaxf(mx, __shfl_xor(mx, 32));
        float mnew  = fmaxf(mrow, mx);
        float alpha = __expf(mrow - mnew);
        mrow = mnew;
        float ps = 0.f;
#pragma unroll
        for (int jt = 0; jt < 4; jt++)
#pragma unroll
            for (int r = 0; r < 4; r++) {
                float pv = __expf(s[jt][r] - mnew);
                s[jt][r] = pv; ps += pv;
            }
        ps += __shfl_xor(ps, 16);
        ps += __shfl_xor(ps, 32);
        lrow = lrow * alpha + ps;
        // redistribute alpha (q=ml space) to C-layout rows (q=g*4+r)
        float ao[4];
#pragma unroll
        for (int r = 0; r < 4; r++) ao[r] = __shfl(alpha, g * 20 + r);
#pragma unroll
        for (int jd = 0; jd < 4; jd++)
#pragma unroll
            for (int r = 0; r < 4; r++) o[jd][r] *= ao[r];
        // P -> LDS: P[q=ml][kv], 4x ds_write_b64 (r=0..3 contiguous)
#pragma unroll
        for (int jt = 0; jt < 4; jt++) {
            half4v pk;
#pragma unroll
            for (int r = 0; r < 4; r++) pk[r] = (half_t)s[jt][r];
            *(half4v*)(Pw + ml * 72 + jt * 16 + g * 4) = pk;
        }
        // PV: A = P (m=q=ml), B = V^T rows (n=d=ml), direct global V loads
#pragma unroll
        for (int kk = 0; kk < 2; kk++) {
            half8 pa = lds_frag(Pw + ml * 72 + kk * 32 + g * 8);
#pragma unroll
            for (int jd = 0; jd < 4; jd++) {
                half8 vb = *(const half8*)(Vg + (size_t)(jd * 16 + ml) * S + kv0 + kk * 32 + g * 8);
                o[jd] = __builtin_amdgcn_mfma_f32_16x16x32_f16(pa, vb, o[jd], 0, 0, 0);
            }
        }
    }

    float inv = 1.f / lrow;
    float io[4];
#pragma unroll
    for (int r = 0; r < 4; r++) io[r] = __shfl(inv, g * 20 + r);
#pragma unroll
    for (int r = 0; r < 4; r++) {
        int row = b * S + qt * 64 + w * 16 + g * 4 + r;
#pragma unroll
        for (int jd = 0; jd < 4; jd++)
            ctx[(size_t)row * H + h * 64 + jd * 16 + ml] = (half_t)(o[jd][r] * io[r]);
    }
}

// ---------------------------------------------------------------------------
// W[K][N] fp32 -> Wt[N][K] fp16 (32x32 tiles), batched over grid.z
// ---------------------------------------------------------------------------
__global__ __launch_bounds__(256) void transpose_cast(
    const float* __restrict__ W, half_t* __restrict__ Wt, int Kd, int Nd)
{
    __shared__ float tile[32][33];
    size_t zoff = (size_t)blockIdx.z * Kd * Nd;
    const float* Wz = W + zoff;
    half_t* Wtz = Wt + zoff;
    int n0 = blockIdx.x * 32, k0 = blockIdx.y * 32;
    int tx = threadIdx.x & 31, ty = threadIdx.x >> 5;
#pragma unroll
    for (int j = 0; j < 4; j++)
        tile[ty + j * 8][tx] = Wz[(size_t)(k0 + ty + j * 8) * Nd + n0 + tx];
    __syncthreads();
#pragma unroll
    for (int j = 0; j < 4; j++)
        Wtz[(size_t)(n0 + ty + j * 8) * Kd + k0 + tx] = (half_t)tile[tx][ty + j * 8];
}

// Q/K/V weights -> per-layer fused [l][3][H][H] transposed fp16
__global__ __launch_bounds__(256) void transpose_qkv(
    const float* __restrict__ Wq, const float* __restrict__ Wk,
    const float* __restrict__ Wv, half_t* __restrict__ WT)
{
    __shared__ float tile[32][33];
    int z = blockIdx.z, l = z / 3, which = z % 3;
    const float* W = ((which == 0) ? Wq : (which == 1) ? Wk : Wv) + (size_t)l * 1024 * 1024;
    half_t* D = WT + ((size_t)l * 3 + which) * 1024 * 1024;
    int n0 = blockIdx.x * 32, k0 = blockIdx.y * 32;
    int tx = threadIdx.x & 31, ty = threadIdx.x >> 5;
#pragma unroll
    for (int j = 0; j < 4; j++)
        tile[ty + j * 8][tx] = W[(size_t)(k0 + ty + j * 8) * 1024 + n0 + tx];
    __syncthreads();
#pragma unroll
    for (int j = 0; j < 4; j++)
        D[(size_t)(n0 + ty + j * 8) * 1024 + k0 + tx] = (half_t)tile[tx][ty + j * 8];
}

__global__ __launch_bounds__(256) void cast_f32_f16(
    const float* __restrict__ in, half_t* __restrict__ out)
{
    int i = blockIdx.x * 256 + threadIdx.x;
    float4 v = ((const float4*)in)[i];
    half4v o; o[0] = (half_t)v.x; o[1] = (half_t)v.y; o[2] = (half_t)v.z; o[3] = (half_t)v.w;
    *(half4v*)(out + (size_t)i * 4) = o;
}

// ---------------------------------------------------------------------------
// LayerNorm over H=1024; emits fp32 (residual path) + fp16 (next GEMM input)
// ---------------------------------------------------------------------------
__global__ __launch_bounds__(256) void layernorm_k(
    const float* __restrict__ in,
    const float* __restrict__ gam, const float* __restrict__ bet,
    float* __restrict__ outf, half_t* __restrict__ outh)
{
    int row = blockIdx.x, tid = threadIdx.x;
    const float4 v = ((const float4*)(in + (size_t)row * 1024))[tid];
    float s = v.x + v.y + v.z + v.w;
    float q = v.x * v.x + v.y * v.y + v.z * v.z + v.w * v.w;
    for (int off = 32; off; off >>= 1) { s += __shfl_down(s, off); q += __shfl_down(q, off); }
    __shared__ float ss[4], sq[4];
    int w = tid >> 6;
    if ((tid & 63) == 0) { ss[w] = s; sq[w] = q; }
    __syncthreads();
    float S_ = ss[0] + ss[1] + ss[2] + ss[3];
    float Q_ = sq[0] + sq[1] + sq[2] + sq[3];
    float mean = S_ * (1.f / 1024.f);
    float var  = Q_ * (1.f / 1024.f) - mean * mean;
    float rstd = rsqrtf(var + 1e-5f);
    float4 gm = ((const float4*)gam)[tid];
    float4 bt = ((const float4*)bet)[tid];
    float y0 = (v.x - mean) * rstd * gm.x + bt.x;
    float y1 = (v.y - mean) * rstd * gm.y + bt.y;
    float y2 = (v.z - mean) * rstd * gm.z + bt.z;
    float y3 = (v.w - mean) * rstd * gm.w + bt.w;
    ((float4*)(outf + (size_t)row * 1024))[tid] = make_float4(y0, y1, y2, y3);
    half4v oh; oh[0] = (half_t)y0; oh[1] = (half_t)y1; oh[2] = (half_t)y2; oh[3] = (half_t)y3;
    *(half4v*)(outh + (size_t)row * 1024 + tid * 4) = oh;
}

// ---------------------------------------------------------------------------
extern "C" void kernel_launch(void* const* d_in, const int* in_sizes, int n_in,
                              void* d_out, int out_size, void* d_ws, size_t ws_size,
                              hipStream_t stream)
{
    const int Lc = 2, Bb = 2, S = 2048, Hh = 1024, NH = 16, FF = 4096;
    const int M = Bb * S;  // 4096

    const float* hs   = (const float*)d_in[0];
    const float* mask = (const float*)d_in[1];
    const float* Wq   = (const float*)d_in[2];  const float* bq  = (const float*)d_in[3];
    const float* Wk   = (const float*)d_in[4];  const float* bk  = (const float*)d_in[5];
    const float* Wv   = (const float*)d_in[6];  const float* bv  = (const float*)d_in[7];
    const float* Wao  = (const float*)d_in[8];  const float* bao = (const float*)d_in[9];
    const float* g1   = (const float*)d_in[10]; const float* b1  = (const float*)d_in[11];
    const float* Wi   = (const float*)d_in[12]; const float* bi  = (const float*)d_in[13];
    const float* Wo   = (const float*)d_in[14]; const float* bo  = (const float*)d_in[15];
    const float* g2   = (const float*)d_in[16]; const float* b2  = (const float*)d_in[17];

    char* p = (char*)d_ws;
    auto take = [&](size_t bytes) { char* r = p; p += (bytes + 255) & ~(size_t)255; return r; };

    half_t* WqkvT = (half_t*)take((size_t)Lc * 3 * Hh * Hh * 2);   // 12 MB
    half_t* WaoT  = (half_t*)take((size_t)Lc * Hh * Hh * 2);       //  4 MB
    half_t* WiT   = (half_t*)take((size_t)Lc * Hh * FF * 2);       // 16 MB
    half_t* WoT   = (half_t*)take((size_t)Lc * FF * Hh * 2);       // 16 MB
    half_t* xb    = (half_t*)take((size_t)M * Hh * 2);             //  8 MB
    half_t* Qb    = (half_t*)take((size_t)M * Hh * 2);             //  8 MB
    half_t* Kb2   = (half_t*)take((size_t)M * Hh * 2);             //  8 MB
    half_t* Vtb   = (half_t*)take((size_t)M * Hh * 2);             //  8 MB
    (void)          take((size_t)M * Hh * 2);                      //  8 MB pad (h1 span)
    half_t* h1    = Qb;   // FFN hidden [M][FF] fp16 reuses Qb..pad (32 MB)
    float*  t0    = (float*)take((size_t)M * Hh * 4);              // 16 MB
    float*  x1f   = (float*)take((size_t)M * Hh * 4);              // 16 MB
    half_t* x1b   = (half_t*)take((size_t)M * Hh * 2);             //  8 MB

    dim3 tb(256);

    transpose_qkv<<<dim3(32, 32, Lc * 3), tb, 0, stream>>>(Wq, Wk, Wv, WqkvT);
    transpose_cast<<<dim3(32, 32, Lc), tb, 0, stream>>>(Wao, WaoT, Hh, Hh);
    transpose_cast<<<dim3(FF / 32, 32, Lc), tb, 0, stream>>>(Wi, WiT, Hh, FF);
    transpose_cast<<<dim3(32, FF / 32, Lc), tb, 0, stream>>>(Wo, WoT, FF, Hh);
    cast_f32_f16<<<dim3(M * Hh / 1024), tb, 0, stream>>>(hs, xb);

    const float* xres = hs;
    for (int l = 0; l < Lc; l++) {
        const half_t* WqkvTl = WqkvT + (size_t)l * 3 * Hh * Hh;
        const half_t* WaoTl  = WaoT  + (size_t)l * Hh * Hh;
        const half_t* WiTl   = WiT   + (size_t)l * Hh * FF;
        const half_t* WoTl   = WoT   + (size_t)l * FF * Hh;

        gemm_qkv<<<dim3(3072 / 128, M / 128), tb, 0, stream>>>(
            xb, WqkvTl, bq + l * Hh, bk + l * Hh, bv + l * Hh, Qb, Kb2, Vtb, M, Hh);

        flash_attn<<<dim3(S / 64, NH, Bb), tb, 0, stream>>>(Qb, Kb2, Vtb, mask, xb, S, Hh);

        gemm_bt64<<<dim3(Hh / 64, M / 128), tb, 0, stream>>>(
            xb, WaoTl, bao + l * Hh, xres, t0, M, Hh, Hh);
        layernorm_k<<<dim3(M), tb, 0, stream>>>(t0, g1 + l * Hh, b1 + l * Hh, x1f, x1b);

        gemm_bt<<<dim3(FF / 128, M / 128), tb, 0, stream>>>(
            x1b, WiTl, bi + l * FF, nullptr, h1, M, FF, Hh, MODE_GELU);
        gemm_bt64<<<dim3(Hh / 64, M / 128), tb, 0, stream>>>(
            h1, WoTl, bo + l * Hh, x1f, t0, M, Hh, FF);

        float* outf = (l == Lc - 1) ? (float*)d_out : x1f;
        layernorm_k<<<dim3(M), tb, 0, stream>>>(t0, g2 + l * Hh, b2 + l * Hh, outf, xb);
        xres = x1f;
    }
}

// Round 3
// 830.230 us; speedup vs baseline: 1.4388x; 1.4388x over previous
//
#include <hip/hip_runtime.h>

typedef _Float16 half_t;
typedef _Float16 half8  __attribute__((ext_vector_type(8)));
typedef _Float16 half4v __attribute__((ext_vector_type(4)));
typedef float    f32x4  __attribute__((ext_vector_type(4)));

#define AS1 __attribute__((address_space(1)))
#define AS3 __attribute__((address_space(3)))

#define MODE_H16  0   // store fp16
#define MODE_F32R 1   // store fp32 = acc + bias + residual
#define MODE_GELU 2   // store fp16 = gelu(acc + bias)

__device__ __forceinline__ f32x4 zero4() {
    f32x4 z; z[0] = 0.f; z[1] = 0.f; z[2] = 0.f; z[3] = 0.f; return z;
}

__device__ __forceinline__ half8 lds_frag(const half_t* p) {
    union { uint4 u; half8 h; } c;
    c.u = *(const uint4*)p;
    return c.h;
}

// async global->LDS, 16B/lane; LDS dest is wave-uniform base + lane*16
__device__ __forceinline__ void gl_lds16(const half_t* g, half_t* l) {
    __builtin_amdgcn_global_load_lds(
        (AS1 unsigned int*)(unsigned long long)(const void*)g,
        (AS3 unsigned int*)l,
        16, 0, 0);
}

// ---------------------------------------------------------------------------
// C[M,N] = A[M,K] @ Bt[N,K]^T + bias, fused epilogues. 128x128 tile, BK=32.
// ---------------------------------------------------------------------------
__global__ __launch_bounds__(256) void gemm_bt(
    const half_t* __restrict__ A,
    const half_t* __restrict__ Bt,
    const float*  __restrict__ bias,
    const float*  __restrict__ res,
    void* __restrict__ out,
    int M, int N, int K, int mode)
{
    __shared__ __align__(16) half_t As[128 * 32];
    __shared__ __align__(16) half_t Bs[128 * 32];

    const int tid  = threadIdx.x;
    const int w    = tid >> 6, lane = tid & 63;
    const int m0   = blockIdx.y * 128, n0 = blockIdx.x * 128;
    const int lr   = lane >> 2;        // 0..15
    const int lc   = (lane & 3) * 8;   // k offset within BK
    const int g    = lane >> 4, ml = lane & 15;
    const int mo   = (w >> 1) * 64, no = (w & 1) * 64;

    f32x4 acc[4][4];
#pragma unroll
    for (int i = 0; i < 4; i++)
#pragma unroll
        for (int j = 0; j < 4; j++) acc[i][j] = zero4();

    const half_t* Ag = A  + (size_t)m0 * K;
    const half_t* Bg = Bt + (size_t)n0 * K;

    for (int k0 = 0; k0 < K; k0 += 32) {
        __syncthreads();
#pragma unroll
        for (int i = 0; i < 2; i++) {
            int r = (w * 2 + i) * 16 + lr;
            gl_lds16(Ag + (size_t)r * K + k0 + lc, &As[(w * 2 + i) * 512]);
            gl_lds16(Bg + (size_t)r * K + k0 + lc, &Bs[(w * 2 + i) * 512]);
        }
        __syncthreads();

        half8 af[4], bf[4];
#pragma unroll
        for (int i = 0; i < 4; i++) af[i] = lds_frag(&As[(mo + i * 16 + ml) * 32 + g * 8]);
#pragma unroll
        for (int j = 0; j < 4; j++) bf[j] = lds_frag(&Bs[(no + j * 16 + ml) * 32 + g * 8]);
#pragma unroll
        for (int i = 0; i < 4; i++)
#pragma unroll
            for (int j = 0; j < 4; j++)
                acc[i][j] = __builtin_amdgcn_mfma_f32_16x16x32_f16(af[i], bf[j], acc[i][j], 0, 0, 0);
    }

    const int gm0 = m0 + mo, gn0 = n0 + no;
#pragma unroll
    for (int j = 0; j < 4; j++) {
        int col = gn0 + j * 16 + ml;
        float bv = bias[col];
#pragma unroll
        for (int i = 0; i < 4; i++) {
#pragma unroll
            for (int r = 0; r < 4; r++) {
                int row = gm0 + i * 16 + g * 4 + r;
                float v = acc[i][j][r] + bv;
                size_t idx = (size_t)row * N + col;
                if (mode == MODE_F32R) {
                    ((float*)out)[idx] = v + res[idx];
                } else if (mode == MODE_GELU) {
                    v = 0.5f * v * (1.f + erff(v * 0.70710678118654752f));
                    ((half_t*)out)[idx] = (half_t)v;
                } else {
                    ((half_t*)out)[idx] = (half_t)v;
                }
            }
        }
    }
}

// ---------------------------------------------------------------------------
// 128x64-tile GEMM for N=1024 cases (2 blocks/CU instead of 1). MODE_F32R.
// ---------------------------------------------------------------------------
__global__ __launch_bounds__(256) void gemm_bt64(
    const half_t* __restrict__ A,
    const half_t* __restrict__ Bt,
    const float*  __restrict__ bias,
    const float*  __restrict__ res,
    float* __restrict__ out,
    int M, int N, int K)
{
    __shared__ __align__(16) half_t As[128 * 32];
    __shared__ __align__(16) half_t Bs[64 * 32];

    const int tid  = threadIdx.x;
    const int w    = tid >> 6, lane = tid & 63;
    const int m0   = blockIdx.y * 128, n0 = blockIdx.x * 64;
    const int lr   = lane >> 2, lc = (lane & 3) * 8;
    const int g    = lane >> 4, ml = lane & 15;
    const int mo   = w * 32;

    f32x4 acc[2][4];
#pragma unroll
    for (int i = 0; i < 2; i++)
#pragma unroll
        for (int j = 0; j < 4; j++) acc[i][j] = zero4();

    const half_t* Ag = A  + (size_t)m0 * K;
    const half_t* Bg = Bt + (size_t)n0 * K;

    for (int k0 = 0; k0 < K; k0 += 32) {
        __syncthreads();
#pragma unroll
        for (int i = 0; i < 2; i++)
            gl_lds16(Ag + (size_t)((w * 2 + i) * 16 + lr) * K + k0 + lc, &As[(w * 2 + i) * 512]);
        gl_lds16(Bg + (size_t)(w * 16 + lr) * K + k0 + lc, &Bs[w * 512]);
        __syncthreads();

        half8 af[2], bf[4];
#pragma unroll
        for (int i = 0; i < 2; i++) af[i] = lds_frag(&As[(mo + i * 16 + ml) * 32 + g * 8]);
#pragma unroll
        for (int j = 0; j < 4; j++) bf[j] = lds_frag(&Bs[(j * 16 + ml) * 32 + g * 8]);
#pragma unroll
        for (int i = 0; i < 2; i++)
#pragma unroll
            for (int j = 0; j < 4; j++)
                acc[i][j] = __builtin_amdgcn_mfma_f32_16x16x32_f16(af[i], bf[j], acc[i][j], 0, 0, 0);
    }

    const int gm0 = m0 + mo;
#pragma unroll
    for (int j = 0; j < 4; j++) {
        int col = n0 + j * 16 + ml;
        float bv = bias[col];
#pragma unroll
        for (int i = 0; i < 2; i++) {
#pragma unroll
            for (int r = 0; r < 4; r++) {
                int row = gm0 + i * 16 + g * 4 + r;
                size_t idx = (size_t)row * N + col;
                out[idx] = acc[i][j][r] + bv + res[idx];
            }
        }
    }
}

// ---------------------------------------------------------------------------
// Fused QKV GEMM: N=3072 (Wq|Wk|Wv transposed, per-layer contiguous).
// cols [0,1024) -> Q fp16, [1024,2048) -> K fp16, [2048,3072) -> V^T fp16.
// ---------------------------------------------------------------------------
__global__ __launch_bounds__(256) void gemm_qkv(
    const half_t* __restrict__ A,
    const half_t* __restrict__ Bt,
    const float*  __restrict__ bq,
    const float*  __restrict__ bk,
    const float*  __restrict__ bv,
    half_t* __restrict__ Qo, half_t* __restrict__ Ko, half_t* __restrict__ Vto,
    int M, int K)
{
    __shared__ __align__(16) half_t As[128 * 32];
    __shared__ __align__(16) half_t Bs[128 * 32];

    const int tid  = threadIdx.x;
    const int w    = tid >> 6, lane = tid & 63;
    const int m0   = blockIdx.y * 128, n0 = blockIdx.x * 128;
    const int lr   = lane >> 2, lc = (lane & 3) * 8;
    const int g    = lane >> 4, ml = lane & 15;
    const int mo   = (w >> 1) * 64, no = (w & 1) * 64;

    f32x4 acc[4][4];
#pragma unroll
    for (int i = 0; i < 4; i++)
#pragma unroll
        for (int j = 0; j < 4; j++) acc[i][j] = zero4();

    const half_t* Ag = A  + (size_t)m0 * K;
    const half_t* Bg = Bt + (size_t)n0 * K;

    for (int k0 = 0; k0 < K; k0 += 32) {
        __syncthreads();
#pragma unroll
        for (int i = 0; i < 2; i++) {
            int r = (w * 2 + i) * 16 + lr;
            gl_lds16(Ag + (size_t)r * K + k0 + lc, &As[(w * 2 + i) * 512]);
            gl_lds16(Bg + (size_t)r * K + k0 + lc, &Bs[(w * 2 + i) * 512]);
        }
        __syncthreads();

        half8 af[4], bf[4];
#pragma unroll
        for (int i = 0; i < 4; i++) af[i] = lds_frag(&As[(mo + i * 16 + ml) * 32 + g * 8]);
#pragma unroll
        for (int j = 0; j < 4; j++) bf[j] = lds_frag(&Bs[(no + j * 16 + ml) * 32 + g * 8]);
#pragma unroll
        for (int i = 0; i < 4; i++)
#pragma unroll
            for (int j = 0; j < 4; j++)
                acc[i][j] = __builtin_amdgcn_mfma_f32_16x16x32_f16(af[i], bf[j], acc[i][j], 0, 0, 0);
    }

    const int seg  = n0 >> 10;                  // block-uniform: 0=Q,1=K,2=V
    const int nloc = (n0 & 1023) + no;
    const float* bias = (seg == 0) ? bq : (seg == 1) ? bk : bv;
    const int gm0 = m0 + mo;

    if (seg < 2) {
        half_t* O = (seg == 0) ? Qo : Ko;
#pragma unroll
        for (int j = 0; j < 4; j++) {
            int col = nloc + j * 16 + ml;
            float bvv = bias[col];
#pragma unroll
            for (int i = 0; i < 4; i++)
#pragma unroll
                for (int r = 0; r < 4; r++)
                    O[(size_t)(gm0 + i * 16 + g * 4 + r) * 1024 + col] =
                        (half_t)(acc[i][j][r] + bvv);
        }
    } else {
#pragma unroll
        for (int j = 0; j < 4; j++) {
            int col = nloc + j * 16 + ml;
            float bvv = bias[col];
#pragma unroll
            for (int i = 0; i < 4; i++) {
                int rowb = gm0 + i * 16 + g * 4;
                int bb = rowb >> 11, sl = rowb & 2047;       // S=2048
                half4v v;
#pragma unroll
                for (int r = 0; r < 4; r++) v[r] = (half_t)(acc[i][j][r] + bvv);
                *(half4v*)&Vto[((size_t)bb * 1024 + col) * 2048 + sl] = v;
            }
        }
    }
}

// ---------------------------------------------------------------------------
// Flash attention v3: S^T softmax + cooperative swizzled LDS staging.
// Block = 4 waves x 32 q = 128 q rows; kv-tiles of 64.
// Q,K: [B*S][H] fp16 ; Vt: [B][H][S] fp16 ; ctx: [B*S][H] fp16.
// Ks/Vs/Ps use 16B-chunk XOR swizzle (chunk ^= row&7) so all ds_read_b128
// land at the 8-words/bank bandwidth floor despite power-of-2 row stride
// (global_load_lds forbids padding: dest = wave base + lane*16).
// ---------------------------------------------------------------------------
__global__ __launch_bounds__(256, 2) void flash_attn(
    const half_t* __restrict__ Q,
    const half_t* __restrict__ Kq,
    const half_t* __restrict__ Vt,
    const float*  __restrict__ mask,   // [B*S] additive
    half_t* __restrict__ ctx,
    int S, int H)
{
    __shared__ __align__(16) half_t Ks[64 * 64];        // [kv][d]   (swizzled)
    __shared__ __align__(16) half_t Vs[64 * 64];        // [d][kv]   (swizzled)
    __shared__ __align__(16) half_t Ps[4 * 32 * 64];    // per-wave P[q][kv] (swizzled)

    const int qt = blockIdx.x, h = blockIdx.y, b = blockIdx.z;
    const int tid = threadIdx.x, w = tid >> 6, lane = tid & 63;
    const int g = lane >> 4, ml = lane & 15, m7 = ml & 7;

    const int q0 = qt * 128 + w * 32;
    const half_t* Qg = Q  + ((size_t)(b * S + q0)) * H + h * 64;
    const half_t* Kg = Kq + ((size_t)b * S) * H + h * 64;
    const half_t* Vg = Vt + ((size_t)b * H + h * 64) * (size_t)S;
    const float*  mk = mask + (size_t)b * S;

    // Q fragments (B-operand): B[n=q(16)][k=d], 2 q-frags x 2 k-chunks
    half8 qf[2][2];
#pragma unroll
    for (int qi = 0; qi < 2; qi++)
#pragma unroll
        for (int kk = 0; kk < 2; kk++)
            qf[qi][kk] = *(const half8*)(Qg + (size_t)(qi * 16 + ml) * H + kk * 32 + g * 8);

    float m_[2] = {-1e30f, -1e30f}, l_[2] = {0.f, 0.f};
    f32x4 o[2][4];
#pragma unroll
    for (int qi = 0; qi < 2; qi++)
#pragma unroll
        for (int df = 0; df < 4; df++) o[qi][df] = zero4();

    half_t* Pw = &Ps[w * 32 * 64];
    const int srow = tid >> 3;            // staging row (round t adds 32)
    const int sc   = tid & 7;             // phys 16B chunk within row

    for (int kv0 = 0; kv0 < S; kv0 += 64) {
        __syncthreads();
#pragma unroll
        for (int t = 0; t < 2; t++) {
            int row = t * 32 + srow;
            int ck  = sc ^ (row & 7);     // source chunk for phys chunk sc
            gl_lds16(Kg + (size_t)(kv0 + row) * H + ck * 8, &Ks[(t * 256 + w * 64) * 8]);
            gl_lds16(Vg + (size_t)row * S + kv0 + ck * 8,   &Vs[(t * 256 + w * 64) * 8]);
        }
        __syncthreads();

        // S^T tiles: mfma(K_frag, Q_frag) -> row = kv-local = g*4+r, col = q = ml
        f32x4 s[2][4];
#pragma unroll
        for (int kvf = 0; kvf < 4; kvf++) {
            half8 k0 = lds_frag(&Ks[(kvf * 16 + ml) * 64 + ((0 + g) ^ m7) * 8]);
            half8 k1 = lds_frag(&Ks[(kvf * 16 + ml) * 64 + ((4 + g) ^ m7) * 8]);
            s[0][kvf] = __builtin_amdgcn_mfma_f32_16x16x32_f16(k0, qf[0][0], zero4(), 0, 0, 0);
            s[0][kvf] = __builtin_amdgcn_mfma_f32_16x16x32_f16(k1, qf[0][1], s[0][kvf], 0, 0, 0);
            s[1][kvf] = __builtin_amdgcn_mfma_f32_16x16x32_f16(k0, qf[1][0], zero4(), 0, 0, 0);
            s[1][kvf] = __builtin_amdgcn_mfma_f32_16x16x32_f16(k1, qf[1][1], s[1][kvf], 0, 0, 0);
        }
        // scale + mask (mask depends on kv only)
#pragma unroll
        for (int kvf = 0; kvf < 4; kvf++) {
            float4 mv = *(const float4*)(mk + kv0 + kvf * 16 + g * 4);
#pragma unroll
            for (int qi = 0; qi < 2; qi++) {
                s[qi][kvf][0] = s[qi][kvf][0] * 0.125f + mv.x;
                s[qi][kvf][1] = s[qi][kvf][1] * 0.125f + mv.y;
                s[qi][kvf][2] = s[qi][kvf][2] * 0.125f + mv.z;
                s[qi][kvf][3] = s[qi][kvf][3] * 0.125f + mv.w;
            }
        }
        float alpha[2];
#pragma unroll
        for (int qi = 0; qi < 2; qi++) {
            float mx = -1e30f;
#pragma unroll
            for (int kvf = 0; kvf < 4; kvf++)
#pragma unroll
                for (int r = 0; r < 4; r++) mx = fmaxf(mx, s[qi][kvf][r]);
            mx = fmaxf(mx, __shfl_xor(mx, 16));
            mx = fmaxf(mx, __shfl_xor(mx, 32));
            float mnew = fmaxf(m_[qi], mx);
            alpha[qi]  = __expf(m_[qi] - mnew);
            m_[qi] = mnew;
            float ps = 0.f;
#pragma unroll
            for (int kvf = 0; kvf < 4; kvf++)
#pragma unroll
                for (int r = 0; r < 4; r++) {
                    float pv = __expf(s[qi][kvf][r] - mnew);
                    s[qi][kvf][r] = pv; ps += pv;
                }
            ps += __shfl_xor(ps, 16);
            ps += __shfl_xor(ps, 32);
            l_[qi] = l_[qi] * alpha[qi] + ps;
            // P write: q = qi*16+ml, kv = kvf*16+g*4+r (half4, swizzled chunk)
#pragma unroll
            for (int kvf = 0; kvf < 4; kvf++) {
                half4v pk;
#pragma unroll
                for (int r = 0; r < 4; r++) pk[r] = (half_t)s[qi][kvf][r];
                *(half4v*)(Pw + (qi * 16 + ml) * 64 +
                           (((kvf * 2 + (g >> 1)) ^ m7) * 8) + (g & 1) * 4) = pk;
            }
        }
        // rescale o: o rows are q = qi*16 + g*4+r -> alpha from lane ml'=g*4+r
#pragma unroll
        for (int qi = 0; qi < 2; qi++) {
#pragma unroll
            for (int r = 0; r < 4; r++) {
                float a = __shfl(alpha[qi], (lane & 48) + g * 4 + r);
#pragma unroll
                for (int df = 0; df < 4; df++) o[qi][df][r] *= a;
            }
        }
        // PV: A = P[q][kv], B = Vs[d][kv]
#pragma unroll
        for (int kk = 0; kk < 2; kk++) {
            half8 pa0 = lds_frag(&Pw[(ml)      * 64 + ((kk * 4 + g) ^ m7) * 8]);
            half8 pa1 = lds_frag(&Pw[(16 + ml) * 64 + ((kk * 4 + g) ^ m7) * 8]);
#pragma unroll
            for (int df = 0; df < 4; df++) {
                half8 vb = lds_frag(&Vs[(df * 16 + ml) * 64 + ((kk * 4 + g) ^ m7) * 8]);
                o[0][df] = __builtin_amdgcn_mfma_f32_16x16x32_f16(pa0, vb, o[0][df], 0, 0, 0);
                o[1][df] = __builtin_amdgcn_mfma_f32_16x16x32_f16(pa1, vb, o[1][df], 0, 0, 0);
            }
        }
    }

#pragma unroll
    for (int qi = 0; qi < 2; qi++) {
        float inv = 1.f / l_[qi];
#pragma unroll
        for (int r = 0; r < 4; r++) {
            float iv = __shfl(inv, (lane & 48) + g * 4 + r);
            int row = b * S + q0 + qi * 16 + g * 4 + r;
#pragma unroll
            for (int df = 0; df < 4; df++)
                ctx[(size_t)row * H + h * 64 + df * 16 + ml] = (half_t)(o[qi][df][r] * iv);
        }
    }
}

// ---------------------------------------------------------------------------
// W[K][N] fp32 -> Wt[N][K] fp16 (32x32 tiles), batched over grid.z
// ---------------------------------------------------------------------------
__global__ __launch_bounds__(256) void transpose_cast(
    const float* __restrict__ W, half_t* __restrict__ Wt, int Kd, int Nd)
{
    __shared__ float tile[32][33];
    size_t zoff = (size_t)blockIdx.z * Kd * Nd;
    const float* Wz = W + zoff;
    half_t* Wtz = Wt + zoff;
    int n0 = blockIdx.x * 32, k0 = blockIdx.y * 32;
    int tx = threadIdx.x & 31, ty = threadIdx.x >> 5;
#pragma unroll
    for (int j = 0; j < 4; j++)
        tile[ty + j * 8][tx] = Wz[(size_t)(k0 + ty + j * 8) * Nd + n0 + tx];
    __syncthreads();
#pragma unroll
    for (int j = 0; j < 4; j++)
        Wtz[(size_t)(n0 + ty + j * 8) * Kd + k0 + tx] = (half_t)tile[tx][ty + j * 8];
}

// Q/K/V weights -> per-layer fused [l][3][H][H] transposed fp16
__global__ __launch_bounds__(256) void transpose_qkv(
    const float* __restrict__ Wq, const float* __restrict__ Wk,
    const float* __restrict__ Wv, half_t* __restrict__ WT)
{
    __shared__ float tile[32][33];
    int z = blockIdx.z, l = z / 3, which = z % 3;
    const float* W = ((which == 0) ? Wq : (which == 1) ? Wk : Wv) + (size_t)l * 1024 * 1024;
    half_t* D = WT + ((size_t)l * 3 + which) * 1024 * 1024;
    int n0 = blockIdx.x * 32, k0 = blockIdx.y * 32;
    int tx = threadIdx.x & 31, ty = threadIdx.x >> 5;
#pragma unroll
    for (int j = 0; j < 4; j++)
        tile[ty + j * 8][tx] = W[(size_t)(k0 + ty + j * 8) * 1024 + n0 + tx];
    __syncthreads();
#pragma unroll
    for (int j = 0; j < 4; j++)
        D[(size_t)(n0 + ty + j * 8) * 1024 + k0 + tx] = (half_t)tile[tx][ty + j * 8];
}

__global__ __launch_bounds__(256) void cast_f32_f16(
    const float* __restrict__ in, half_t* __restrict__ out)
{
    int i = blockIdx.x * 256 + threadIdx.x;
    float4 v = ((const float4*)in)[i];
    half4v o; o[0] = (half_t)v.x; o[1] = (half_t)v.y; o[2] = (half_t)v.z; o[3] = (half_t)v.w;
    *(half4v*)(out + (size_t)i * 4) = o;
}

// ---------------------------------------------------------------------------
// LayerNorm over H=1024; emits fp32 (residual path) + fp16 (next GEMM input)
// ---------------------------------------------------------------------------
__global__ __launch_bounds__(256) void layernorm_k(
    const float* __restrict__ in,
    const float* __restrict__ gam, const float* __restrict__ bet,
    float* __restrict__ outf, half_t* __restrict__ outh)
{
    int row = blockIdx.x, tid = threadIdx.x;
    const float4 v = ((const float4*)(in + (size_t)row * 1024))[tid];
    float s = v.x + v.y + v.z + v.w;
    float q = v.x * v.x + v.y * v.y + v.z * v.z + v.w * v.w;
    for (int off = 32; off; off >>= 1) { s += __shfl_down(s, off); q += __shfl_down(q, off); }
    __shared__ float ss[4], sq[4];
    int w = tid >> 6;
    if ((tid & 63) == 0) { ss[w] = s; sq[w] = q; }
    __syncthreads();
    float S_ = ss[0] + ss[1] + ss[2] + ss[3];
    float Q_ = sq[0] + sq[1] + sq[2] + sq[3];
    float mean = S_ * (1.f / 1024.f);
    float var  = Q_ * (1.f / 1024.f) - mean * mean;
    float rstd = rsqrtf(var + 1e-5f);
    float4 gm = ((const float4*)gam)[tid];
    float4 bt = ((const float4*)bet)[tid];
    float y0 = (v.x - mean) * rstd * gm.x + bt.x;
    float y1 = (v.y - mean) * rstd * gm.y + bt.y;
    float y2 = (v.z - mean) * rstd * gm.z + bt.z;
    float y3 = (v.w - mean) * rstd * gm.w + bt.w;
    ((float4*)(outf + (size_t)row * 1024))[tid] = make_float4(y0, y1, y2, y3);
    half4v oh; oh[0] = (half_t)y0; oh[1] = (half_t)y1; oh[2] = (half_t)y2; oh[3] = (half_t)y3;
    *(half4v*)(outh + (size_t)row * 1024 + tid * 4) = oh;
}

// ---------------------------------------------------------------------------
extern "C" void kernel_launch(void* const* d_in, const int* in_sizes, int n_in,
                              void* d_out, int out_size, void* d_ws, size_t ws_size,
                              hipStream_t stream)
{
    const int Lc = 2, Bb = 2, S = 2048, Hh = 1024, NH = 16, FF = 4096;
    const int M = Bb * S;  // 4096

    const float* hs   = (const float*)d_in[0];
    const float* mask = (const float*)d_in[1];
    const float* Wq   = (const float*)d_in[2];  const float* bq  = (const float*)d_in[3];
    const float* Wk   = (const float*)d_in[4];  const float* bk  = (const float*)d_in[5];
    const float* Wv   = (const float*)d_in[6];  const float* bv  = (const float*)d_in[7];
    const float* Wao  = (const float*)d_in[8];  const float* bao = (const float*)d_in[9];
    const float* g1   = (const float*)d_in[10]; const float* b1  = (const float*)d_in[11];
    const float* Wi   = (const float*)d_in[12]; const float* bi  = (const float*)d_in[13];
    const float* Wo   = (const float*)d_in[14]; const float* bo  = (const float*)d_in[15];
    const float* g2   = (const float*)d_in[16]; const float* b2  = (const float*)d_in[17];

    char* p = (char*)d_ws;
    auto take = [&](size_t bytes) { char* r = p; p += (bytes + 255) & ~(size_t)255; return r; };

    half_t* WqkvT = (half_t*)take((size_t)Lc * 3 * Hh * Hh * 2);   // 12 MB
    half_t* WaoT  = (half_t*)take((size_t)Lc * Hh * Hh * 2);       //  4 MB
    half_t* WiT   = (half_t*)take((size_t)Lc * Hh * FF * 2);       // 16 MB
    half_t* WoT   = (half_t*)take((size_t)Lc * FF * Hh * 2);       // 16 MB
    half_t* xb    = (half_t*)take((size_t)M * Hh * 2);             //  8 MB
    half_t* Qb    = (half_t*)take((size_t)M * Hh * 2);             //  8 MB
    half_t* Kb2   = (half_t*)take((size_t)M * Hh * 2);             //  8 MB
    half_t* Vtb   = (half_t*)take((size_t)M * Hh * 2);             //  8 MB
    (void)          take((size_t)M * Hh * 2);                      //  8 MB pad (h1 span)
    half_t* h1    = Qb;   // FFN hidden [M][FF] fp16 reuses Qb..pad (32 MB)
    float*  t0    = (float*)take((size_t)M * Hh * 4);              // 16 MB
    float*  x1f   = (float*)take((size_t)M * Hh * 4);              // 16 MB
    half_t* x1b   = (half_t*)take((size_t)M * Hh * 2);             //  8 MB

    dim3 tb(256);

    transpose_qkv<<<dim3(32, 32, Lc * 3), tb, 0, stream>>>(Wq, Wk, Wv, WqkvT);
    transpose_cast<<<dim3(32, 32, Lc), tb, 0, stream>>>(Wao, WaoT, Hh, Hh);
    transpose_cast<<<dim3(FF / 32, 32, Lc), tb, 0, stream>>>(Wi, WiT, Hh, FF);
    transpose_cast<<<dim3(32, FF / 32, Lc), tb, 0, stream>>>(Wo, WoT, FF, Hh);
    cast_f32_f16<<<dim3(M * Hh / 1024), tb, 0, stream>>>(hs, xb);

    const float* xres = hs;
    for (int l = 0; l < Lc; l++) {
        const half_t* WqkvTl = WqkvT + (size_t)l * 3 * Hh * Hh;
        const half_t* WaoTl  = WaoT  + (size_t)l * Hh * Hh;
        const half_t* WiTl   = WiT   + (size_t)l * Hh * FF;
        const half_t* WoTl   = WoT   + (size_t)l * FF * Hh;

        gemm_qkv<<<dim3(3072 / 128, M / 128), tb, 0, stream>>>(
            xb, WqkvTl, bq + l * Hh, bk + l * Hh, bv + l * Hh, Qb, Kb2, Vtb, M, Hh);

        flash_attn<<<dim3(S / 128, NH, Bb), tb, 0, stream>>>(Qb, Kb2, Vtb, mask, xb, S, Hh);

        gemm_bt64<<<dim3(Hh / 64, M / 128), tb, 0, stream>>>(
            xb, WaoTl, bao + l * Hh, xres, t0, M, Hh, Hh);
        layernorm_k<<<dim3(M), tb, 0, stream>>>(t0, g1 + l * Hh, b1 + l * Hh, x1f, x1b);

        gemm_bt<<<dim3(FF / 128, M / 128), tb, 0, stream>>>(
            x1b, WiTl, bi + l * FF, nullptr, h1, M, FF, Hh, MODE_GELU);
        gemm_bt64<<<dim3(Hh / 64, M / 128), tb, 0, stream>>>(
            h1, WoTl, bo + l * Hh, x1f, t0, M, Hh, FF);

        float* outf = (l == Lc - 1) ? (float*)d_out : x1f;
        layernorm_k<<<dim3(M), tb, 0, stream>>>(t0, g2 + l * Hh, b2 + l * Hh, outf, xb);
        xres = x1f;
    }
}

// Round 4
// 749.530 us; speedup vs baseline: 1.5937x; 1.1077x over previous
//
#include <hip/hip_runtime.h>

typedef _Float16 half_t;
typedef _Float16 half8  __attribute__((ext_vector_type(8)));
typedef _Float16 half4v __attribute__((ext_vector_type(4)));
typedef float    f32x4  __attribute__((ext_vector_type(4)));

#define AS1 __attribute__((address_space(1)))
#define AS3 __attribute__((address_space(3)))

#define MODE_H16  0   // store fp16
#define MODE_F32R 1   // store fp32 = acc + bias + residual
#define MODE_GELU 2   // store fp16 = gelu(acc + bias)

__device__ __forceinline__ f32x4 zero4() {
    f32x4 z; z[0] = 0.f; z[1] = 0.f; z[2] = 0.f; z[3] = 0.f; return z;
}

__device__ __forceinline__ half8 lds_frag(const half_t* p) {
    union { uint4 u; half8 h; } c;
    c.u = *(const uint4*)p;
    return c.h;
}

// fast tanh-GELU: v*sigmoid(1.59577(v+0.044715 v^3)); |err| ~3e-4
__device__ __forceinline__ float gelu_f(float v) {
    float t = v * v;
    float u = v * (1.595769122f + 0.0713548163f * t);
    return v / (1.f + __expf(-u));
}

// async global->LDS, 16B/lane; LDS dest is wave-uniform base + lane*16
__device__ __forceinline__ void gl_lds16(const half_t* g, half_t* l) {
    __builtin_amdgcn_global_load_lds(
        (AS1 unsigned int*)(unsigned long long)(const void*)g,
        (AS3 unsigned int*)l,
        16, 0, 0);
}

// ---------------------------------------------------------------------------
// BK=64 swizzled tiles: logical chunk c (8 els) of row r lives at phys chunk
// c^(r&7). Staging: lane -> row lane>>3, source chunk (lane&7)^((lane>>3)&7).
// Fragment read of k-chunk (kk*4+g) of row: phys chunk (kk*4+g)^(row&7);
// row&7 == ml&7 for all our row patterns. 16-lane read phase covers all 32
// banks at 2 lanes/chunk -> free 2-way (m136) vs 8-way for naive layout.
// ---------------------------------------------------------------------------

// C[M,N] = A[M,K] @ Bt[N,K]^T + bias, fused epilogues. 128x128 tile, BK=64.
__global__ __launch_bounds__(256) void gemm_bt(
    const half_t* __restrict__ A,
    const half_t* __restrict__ Bt,
    const float*  __restrict__ bias,
    const float*  __restrict__ res,
    void* __restrict__ out,
    int M, int N, int K, int mode)
{
    __shared__ __align__(16) half_t As[128 * 64];
    __shared__ __align__(16) half_t Bs[128 * 64];

    const int tid  = threadIdx.x;
    const int w    = tid >> 6, lane = tid & 63;
    const int m0   = blockIdx.y * 128, n0 = blockIdx.x * 128;
    const int g    = lane >> 4, ml = lane & 15, m7 = ml & 7;
    const int mo   = (w >> 1) * 64, no = (w & 1) * 64;
    const int r8   = lane >> 3;                    // staging row within 8-group
    const int sck  = ((lane & 7) ^ (r8 & 7)) * 8;  // staging source chunk offset

    f32x4 acc[4][4];
#pragma unroll
    for (int i = 0; i < 4; i++)
#pragma unroll
        for (int j = 0; j < 4; j++) acc[i][j] = zero4();

    const half_t* Ag = A  + (size_t)m0 * K;
    const half_t* Bg = Bt + (size_t)n0 * K;

    for (int k0 = 0; k0 < K; k0 += 64) {
        __syncthreads();
#pragma unroll
        for (int i = 0; i < 4; i++) {
            int t = w * 4 + i;
            gl_lds16(Ag + (size_t)(t * 8 + r8) * K + k0 + sck, &As[t * 512]);
            gl_lds16(Bg + (size_t)(t * 8 + r8) * K + k0 + sck, &Bs[t * 512]);
        }
        __syncthreads();
#pragma unroll
        for (int kk = 0; kk < 2; kk++) {
            const int co = ((kk * 4 + g) ^ m7) * 8;
            half8 af[4], bf[4];
#pragma unroll
            for (int i = 0; i < 4; i++) af[i] = lds_frag(&As[(mo + i * 16 + ml) * 64 + co]);
#pragma unroll
            for (int j = 0; j < 4; j++) bf[j] = lds_frag(&Bs[(no + j * 16 + ml) * 64 + co]);
#pragma unroll
            for (int i = 0; i < 4; i++)
#pragma unroll
                for (int j = 0; j < 4; j++)
                    acc[i][j] = __builtin_amdgcn_mfma_f32_16x16x32_f16(af[i], bf[j], acc[i][j], 0, 0, 0);
        }
    }

    const int gm0 = m0 + mo, gn0 = n0 + no;
#pragma unroll
    for (int j = 0; j < 4; j++) {
        int col = gn0 + j * 16 + ml;
        float bv = bias[col];
#pragma unroll
        for (int i = 0; i < 4; i++) {
#pragma unroll
            for (int r = 0; r < 4; r++) {
                int row = gm0 + i * 16 + g * 4 + r;
                float v = acc[i][j][r] + bv;
                size_t idx = (size_t)row * N + col;
                if (mode == MODE_F32R) {
                    ((float*)out)[idx] = v + res[idx];
                } else if (mode == MODE_GELU) {
                    ((half_t*)out)[idx] = (half_t)gelu_f(v);
                } else {
                    ((half_t*)out)[idx] = (half_t)v;
                }
            }
        }
    }
}

// ---------------------------------------------------------------------------
// 128x64-tile GEMM for N=1024 cases (more blocks/CU). BK=64. MODE_F32R only.
// ---------------------------------------------------------------------------
__global__ __launch_bounds__(256) void gemm_bt64(
    const half_t* __restrict__ A,
    const half_t* __restrict__ Bt,
    const float*  __restrict__ bias,
    const float*  __restrict__ res,
    float* __restrict__ out,
    int M, int N, int K)
{
    __shared__ __align__(16) half_t As[128 * 64];
    __shared__ __align__(16) half_t Bs[64 * 64];

    const int tid  = threadIdx.x;
    const int w    = tid >> 6, lane = tid & 63;
    const int m0   = blockIdx.y * 128, n0 = blockIdx.x * 64;
    const int g    = lane >> 4, ml = lane & 15, m7 = ml & 7;
    const int mo   = w * 32;
    const int r8   = lane >> 3;
    const int sck  = ((lane & 7) ^ (r8 & 7)) * 8;

    f32x4 acc[2][4];
#pragma unroll
    for (int i = 0; i < 2; i++)
#pragma unroll
        for (int j = 0; j < 4; j++) acc[i][j] = zero4();

    const half_t* Ag = A  + (size_t)m0 * K;
    const half_t* Bg = Bt + (size_t)n0 * K;

    for (int k0 = 0; k0 < K; k0 += 64) {
        __syncthreads();
#pragma unroll
        for (int i = 0; i < 4; i++) {
            int t = w * 4 + i;
            gl_lds16(Ag + (size_t)(t * 8 + r8) * K + k0 + sck, &As[t * 512]);
        }
#pragma unroll
        for (int i = 0; i < 2; i++) {
            int t = w * 2 + i;
            gl_lds16(Bg + (size_t)(t * 8 + r8) * K + k0 + sck, &Bs[t * 512]);
        }
        __syncthreads();
#pragma unroll
        for (int kk = 0; kk < 2; kk++) {
            const int co = ((kk * 4 + g) ^ m7) * 8;
            half8 af[2], bf[4];
#pragma unroll
            for (int i = 0; i < 2; i++) af[i] = lds_frag(&As[(mo + i * 16 + ml) * 64 + co]);
#pragma unroll
            for (int j = 0; j < 4; j++) bf[j] = lds_frag(&Bs[(j * 16 + ml) * 64 + co]);
#pragma unroll
            for (int i = 0; i < 2; i++)
#pragma unroll
                for (int j = 0; j < 4; j++)
                    acc[i][j] = __builtin_amdgcn_mfma_f32_16x16x32_f16(af[i], bf[j], acc[i][j], 0, 0, 0);
        }
    }

    const int gm0 = m0 + mo;
#pragma unroll
    for (int j = 0; j < 4; j++) {
        int col = n0 + j * 16 + ml;
        float bv = bias[col];
#pragma unroll
        for (int i = 0; i < 2; i++) {
#pragma unroll
            for (int r = 0; r < 4; r++) {
                int row = gm0 + i * 16 + g * 4 + r;
                size_t idx = (size_t)row * N + col;
                out[idx] = acc[i][j][r] + bv + res[idx];
            }
        }
    }
}

// ---------------------------------------------------------------------------
// Fused QKV GEMM: N=3072 (Wq|Wk|Wv transposed, per-layer contiguous). BK=64.
// cols [0,1024) -> Q fp16, [1024,2048) -> K fp16, [2048,3072) -> V^T fp16.
// ---------------------------------------------------------------------------
__global__ __launch_bounds__(256) void gemm_qkv(
    const half_t* __restrict__ A,
    const half_t* __restrict__ Bt,
    const float*  __restrict__ bq,
    const float*  __restrict__ bk,
    const float*  __restrict__ bv,
    half_t* __restrict__ Qo, half_t* __restrict__ Ko, half_t* __restrict__ Vto,
    int M, int K)
{
    __shared__ __align__(16) half_t As[128 * 64];
    __shared__ __align__(16) half_t Bs[128 * 64];

    const int tid  = threadIdx.x;
    const int w    = tid >> 6, lane = tid & 63;
    const int m0   = blockIdx.y * 128, n0 = blockIdx.x * 128;
    const int g    = lane >> 4, ml = lane & 15, m7 = ml & 7;
    const int mo   = (w >> 1) * 64, no = (w & 1) * 64;
    const int r8   = lane >> 3;
    const int sck  = ((lane & 7) ^ (r8 & 7)) * 8;

    f32x4 acc[4][4];
#pragma unroll
    for (int i = 0; i < 4; i++)
#pragma unroll
        for (int j = 0; j < 4; j++) acc[i][j] = zero4();

    const half_t* Ag = A  + (size_t)m0 * K;
    const half_t* Bg = Bt + (size_t)n0 * K;

    for (int k0 = 0; k0 < K; k0 += 64) {
        __syncthreads();
#pragma unroll
        for (int i = 0; i < 4; i++) {
            int t = w * 4 + i;
            gl_lds16(Ag + (size_t)(t * 8 + r8) * K + k0 + sck, &As[t * 512]);
            gl_lds16(Bg + (size_t)(t * 8 + r8) * K + k0 + sck, &Bs[t * 512]);
        }
        __syncthreads();
#pragma unroll
        for (int kk = 0; kk < 2; kk++) {
            const int co = ((kk * 4 + g) ^ m7) * 8;
            half8 af[4], bf[4];
#pragma unroll
            for (int i = 0; i < 4; i++) af[i] = lds_frag(&As[(mo + i * 16 + ml) * 64 + co]);
#pragma unroll
            for (int j = 0; j < 4; j++) bf[j] = lds_frag(&Bs[(no + j * 16 + ml) * 64 + co]);
#pragma unroll
            for (int i = 0; i < 4; i++)
#pragma unroll
                for (int j = 0; j < 4; j++)
                    acc[i][j] = __builtin_amdgcn_mfma_f32_16x16x32_f16(af[i], bf[j], acc[i][j], 0, 0, 0);
        }
    }

    const int seg  = n0 >> 10;                  // block-uniform: 0=Q,1=K,2=V
    const int nloc = (n0 & 1023) + no;
    const float* bias = (seg == 0) ? bq : (seg == 1) ? bk : bv;
    const int gm0 = m0 + mo;

    if (seg < 2) {
        half_t* O = (seg == 0) ? Qo : Ko;
#pragma unroll
        for (int j = 0; j < 4; j++) {
            int col = nloc + j * 16 + ml;
            float bvv = bias[col];
#pragma unroll
            for (int i = 0; i < 4; i++)
#pragma unroll
                for (int r = 0; r < 4; r++)
                    O[(size_t)(gm0 + i * 16 + g * 4 + r) * 1024 + col] =
                        (half_t)(acc[i][j][r] + bvv);
        }
    } else {
#pragma unroll
        for (int j = 0; j < 4; j++) {
            int col = nloc + j * 16 + ml;
            float bvv = bias[col];
#pragma unroll
            for (int i = 0; i < 4; i++) {
                int rowb = gm0 + i * 16 + g * 4;
                int bb = rowb >> 11, sl = rowb & 2047;       // S=2048
                half4v v;
#pragma unroll
                for (int r = 0; r < 4; r++) v[r] = (half_t)(acc[i][j][r] + bvv);
                *(half4v*)&Vto[((size_t)bb * 1024 + col) * 2048 + sl] = v;
            }
        }
    }
}

// ---------------------------------------------------------------------------
// Flash attention v3: S^T softmax + cooperative swizzled LDS staging.
// Block = 4 waves x 32 q = 128 q rows; kv-tiles of 64.
// Q,K: [B*S][H] fp16 ; Vt: [B][H][S] fp16 ; ctx: [B*S][H] fp16.
// ---------------------------------------------------------------------------
__global__ __launch_bounds__(256, 2) void flash_attn(
    const half_t* __restrict__ Q,
    const half_t* __restrict__ Kq,
    const half_t* __restrict__ Vt,
    const float*  __restrict__ mask,   // [B*S] additive
    half_t* __restrict__ ctx,
    int S, int H)
{
    __shared__ __align__(16) half_t Ks[64 * 64];        // [kv][d]   (swizzled)
    __shared__ __align__(16) half_t Vs[64 * 64];        // [d][kv]   (swizzled)
    __shared__ __align__(16) half_t Ps[4 * 32 * 64];    // per-wave P[q][kv] (swizzled)

    const int qt = blockIdx.x, h = blockIdx.y, b = blockIdx.z;
    const int tid = threadIdx.x, w = tid >> 6, lane = tid & 63;
    const int g = lane >> 4, ml = lane & 15, m7 = ml & 7;

    const int q0 = qt * 128 + w * 32;
    const half_t* Qg = Q  + ((size_t)(b * S + q0)) * H + h * 64;
    const half_t* Kg = Kq + ((size_t)b * S) * H + h * 64;
    const half_t* Vg = Vt + ((size_t)b * H + h * 64) * (size_t)S;
    const float*  mk = mask + (size_t)b * S;

    half8 qf[2][2];
#pragma unroll
    for (int qi = 0; qi < 2; qi++)
#pragma unroll
        for (int kk = 0; kk < 2; kk++)
            qf[qi][kk] = *(const half8*)(Qg + (size_t)(qi * 16 + ml) * H + kk * 32 + g * 8);

    float m_[2] = {-1e30f, -1e30f}, l_[2] = {0.f, 0.f};
    f32x4 o[2][4];
#pragma unroll
    for (int qi = 0; qi < 2; qi++)
#pragma unroll
        for (int df = 0; df < 4; df++) o[qi][df] = zero4();

    half_t* Pw = &Ps[w * 32 * 64];
    const int srow = tid >> 3;            // staging row (round t adds 32)
    const int sc   = tid & 7;             // phys 16B chunk within row

    for (int kv0 = 0; kv0 < S; kv0 += 64) {
        __syncthreads();
#pragma unroll
        for (int t = 0; t < 2; t++) {
            int row = t * 32 + srow;
            int ck  = sc ^ (row & 7);     // source chunk for phys chunk sc
            gl_lds16(Kg + (size_t)(kv0 + row) * H + ck * 8, &Ks[(t * 256 + w * 64) * 8]);
            gl_lds16(Vg + (size_t)row * S + kv0 + ck * 8,   &Vs[(t * 256 + w * 64) * 8]);
        }
        __syncthreads();

        f32x4 s[2][4];
#pragma unroll
        for (int kvf = 0; kvf < 4; kvf++) {
            half8 k0 = lds_frag(&Ks[(kvf * 16 + ml) * 64 + ((0 + g) ^ m7) * 8]);
            half8 k1 = lds_frag(&Ks[(kvf * 16 + ml) * 64 + ((4 + g) ^ m7) * 8]);
            s[0][kvf] = __builtin_amdgcn_mfma_f32_16x16x32_f16(k0, qf[0][0], zero4(), 0, 0, 0);
            s[0][kvf] = __builtin_amdgcn_mfma_f32_16x16x32_f16(k1, qf[0][1], s[0][kvf], 0, 0, 0);
            s[1][kvf] = __builtin_amdgcn_mfma_f32_16x16x32_f16(k0, qf[1][0], zero4(), 0, 0, 0);
            s[1][kvf] = __builtin_amdgcn_mfma_f32_16x16x32_f16(k1, qf[1][1], s[1][kvf], 0, 0, 0);
        }
#pragma unroll
        for (int kvf = 0; kvf < 4; kvf++) {
            float4 mv = *(const float4*)(mk + kv0 + kvf * 16 + g * 4);
#pragma unroll
            for (int qi = 0; qi < 2; qi++) {
                s[qi][kvf][0] = s[qi][kvf][0] * 0.125f + mv.x;
                s[qi][kvf][1] = s[qi][kvf][1] * 0.125f + mv.y;
                s[qi][kvf][2] = s[qi][kvf][2] * 0.125f + mv.z;
                s[qi][kvf][3] = s[qi][kvf][3] * 0.125f + mv.w;
            }
        }
        float alpha[2];
#pragma unroll
        for (int qi = 0; qi < 2; qi++) {
            float mx = -1e30f;
#pragma unroll
            for (int kvf = 0; kvf < 4; kvf++)
#pragma unroll
                for (int r = 0; r < 4; r++) mx = fmaxf(mx, s[qi][kvf][r]);
            mx = fmaxf(mx, __shfl_xor(mx, 16));
            mx = fmaxf(mx, __shfl_xor(mx, 32));
            float mnew = fmaxf(m_[qi], mx);
            alpha[qi]  = __expf(m_[qi] - mnew);
            m_[qi] = mnew;
            float ps = 0.f;
#pragma unroll
            for (int kvf = 0; kvf < 4; kvf++)
#pragma unroll
                for (int r = 0; r < 4; r++) {
                    float pv = __expf(s[qi][kvf][r] - mnew);
                    s[qi][kvf][r] = pv; ps += pv;
                }
            ps += __shfl_xor(ps, 16);
            ps += __shfl_xor(ps, 32);
            l_[qi] = l_[qi] * alpha[qi] + ps;
#pragma unroll
            for (int kvf = 0; kvf < 4; kvf++) {
                half4v pk;
#pragma unroll
                for (int r = 0; r < 4; r++) pk[r] = (half_t)s[qi][kvf][r];
                *(half4v*)(Pw + (qi * 16 + ml) * 64 +
                           (((kvf * 2 + (g >> 1)) ^ m7) * 8) + (g & 1) * 4) = pk;
            }
        }
#pragma unroll
        for (int qi = 0; qi < 2; qi++) {
#pragma unroll
            for (int r = 0; r < 4; r++) {
                float a = __shfl(alpha[qi], (lane & 48) + g * 4 + r);
#pragma unroll
                for (int df = 0; df < 4; df++) o[qi][df][r] *= a;
            }
        }
#pragma unroll
        for (int kk = 0; kk < 2; kk++) {
            half8 pa0 = lds_frag(&Pw[(ml)      * 64 + ((kk * 4 + g) ^ m7) * 8]);
            half8 pa1 = lds_frag(&Pw[(16 + ml) * 64 + ((kk * 4 + g) ^ m7) * 8]);
#pragma unroll
            for (int df = 0; df < 4; df++) {
                half8 vb = lds_frag(&Vs[(df * 16 + ml) * 64 + ((kk * 4 + g) ^ m7) * 8]);
                o[0][df] = __builtin_amdgcn_mfma_f32_16x16x32_f16(pa0, vb, o[0][df], 0, 0, 0);
                o[1][df] = __builtin_amdgcn_mfma_f32_16x16x32_f16(pa1, vb, o[1][df], 0, 0, 0);
            }
        }
    }

#pragma unroll
    for (int qi = 0; qi < 2; qi++) {
        float inv = 1.f / l_[qi];
#pragma unroll
        for (int r = 0; r < 4; r++) {
            float iv = __shfl(inv, (lane & 48) + g * 4 + r);
            int row = b * S + q0 + qi * 16 + g * 4 + r;
#pragma unroll
            for (int df = 0; df < 4; df++)
                ctx[(size_t)row * H + h * 64 + df * 16 + ml] = (half_t)(o[qi][df][r] * iv);
        }
    }
}

// ---------------------------------------------------------------------------
// W[K][N] fp32 -> Wt[N][K] fp16 (32x32 tiles), batched over grid.z
// ---------------------------------------------------------------------------
__global__ __launch_bounds__(256) void transpose_cast(
    const float* __restrict__ W, half_t* __restrict__ Wt, int Kd, int Nd)
{
    __shared__ float tile[32][33];
    size_t zoff = (size_t)blockIdx.z * Kd * Nd;
    const float* Wz = W + zoff;
    half_t* Wtz = Wt + zoff;
    int n0 = blockIdx.x * 32, k0 = blockIdx.y * 32;
    int tx = threadIdx.x & 31, ty = threadIdx.x >> 5;
#pragma unroll
    for (int j = 0; j < 4; j++)
        tile[ty + j * 8][tx] = Wz[(size_t)(k0 + ty + j * 8) * Nd + n0 + tx];
    __syncthreads();
#pragma unroll
    for (int j = 0; j < 4; j++)
        Wtz[(size_t)(n0 + ty + j * 8) * Kd + k0 + tx] = (half_t)tile[tx][ty + j * 8];
}

// Q/K/V weights -> per-layer fused [l][3][H][H] transposed fp16
__global__ __launch_bounds__(256) void transpose_qkv(
    const float* __restrict__ Wq, const float* __restrict__ Wk,
    const float* __restrict__ Wv, half_t* __restrict__ WT)
{
    __shared__ float tile[32][33];
    int z = blockIdx.z, l = z / 3, which = z % 3;
    const float* W = ((which == 0) ? Wq : (which == 1) ? Wk : Wv) + (size_t)l * 1024 * 1024;
    half_t* D = WT + ((size_t)l * 3 + which) * 1024 * 1024;
    int n0 = blockIdx.x * 32, k0 = blockIdx.y * 32;
    int tx = threadIdx.x & 31, ty = threadIdx.x >> 5;
#pragma unroll
    for (int j = 0; j < 4; j++)
        tile[ty + j * 8][tx] = W[(size_t)(k0 + ty + j * 8) * 1024 + n0 + tx];
    __syncthreads();
#pragma unroll
    for (int j = 0; j < 4; j++)
        D[(size_t)(n0 + ty + j * 8) * 1024 + k0 + tx] = (half_t)tile[tx][ty + j * 8];
}

__global__ __launch_bounds__(256) void cast_f32_f16(
    const float* __restrict__ in, half_t* __restrict__ out)
{
    int i = blockIdx.x * 256 + threadIdx.x;
    float4 v = ((const float4*)in)[i];
    half4v o; o[0] = (half_t)v.x; o[1] = (half_t)v.y; o[2] = (half_t)v.z; o[3] = (half_t)v.w;
    *(half4v*)(out + (size_t)i * 4) = o;
}

// ---------------------------------------------------------------------------
// LayerNorm over H=1024; emits fp32 (residual path) + fp16 (next GEMM input)
// ---------------------------------------------------------------------------
__global__ __launch_bounds__(256) void layernorm_k(
    const float* __restrict__ in,
    const float* __restrict__ gam, const float* __restrict__ bet,
    float* __restrict__ outf, half_t* __restrict__ outh)
{
    int row = blockIdx.x, tid = threadIdx.x;
    const float4 v = ((const float4*)(in + (size_t)row * 1024))[tid];
    float s = v.x + v.y + v.z + v.w;
    float q = v.x * v.x + v.y * v.y + v.z * v.z + v.w * v.w;
    for (int off = 32; off; off >>= 1) { s += __shfl_down(s, off); q += __shfl_down(q, off); }
    __shared__ float ss[4], sq[4];
    int w = tid >> 6;
    if ((tid & 63) == 0) { ss[w] = s; sq[w] = q; }
    __syncthreads();
    float S_ = ss[0] + ss[1] + ss[2] + ss[3];
    float Q_ = sq[0] + sq[1] + sq[2] + sq[3];
    float mean = S_ * (1.f / 1024.f);
    float var  = Q_ * (1.f / 1024.f) - mean * mean;
    float rstd = rsqrtf(var + 1e-5f);
    float4 gm = ((const float4*)gam)[tid];
    float4 bt = ((const float4*)bet)[tid];
    float y0 = (v.x - mean) * rstd * gm.x + bt.x;
    float y1 = (v.y - mean) * rstd * gm.y + bt.y;
    float y2 = (v.z - mean) * rstd * gm.z + bt.z;
    float y3 = (v.w - mean) * rstd * gm.w + bt.w;
    ((float4*)(outf + (size_t)row * 1024))[tid] = make_float4(y0, y1, y2, y3);
    half4v oh; oh[0] = (half_t)y0; oh[1] = (half_t)y1; oh[2] = (half_t)y2; oh[3] = (half_t)y3;
    *(half4v*)(outh + (size_t)row * 1024 + tid * 4) = oh;
}

// ---------------------------------------------------------------------------
extern "C" void kernel_launch(void* const* d_in, const int* in_sizes, int n_in,
                              void* d_out, int out_size, void* d_ws, size_t ws_size,
                              hipStream_t stream)
{
    const int Lc = 2, Bb = 2, S = 2048, Hh = 1024, NH = 16, FF = 4096;
    const int M = Bb * S;  // 4096

    const float* hs   = (const float*)d_in[0];
    const float* mask = (const float*)d_in[1];
    const float* Wq   = (const float*)d_in[2];  const float* bq  = (const float*)d_in[3];
    const float* Wk   = (const float*)d_in[4];  const float* bk  = (const float*)d_in[5];
    const float* Wv   = (const float*)d_in[6];  const float* bv  = (const float*)d_in[7];
    const float* Wao  = (const float*)d_in[8];  const float* bao = (const float*)d_in[9];
    const float* g1   = (const float*)d_in[10]; const float* b1  = (const float*)d_in[11];
    const float* Wi   = (const float*)d_in[12]; const float* bi  = (const float*)d_in[13];
    const float* Wo   = (const float*)d_in[14]; const float* bo  = (const float*)d_in[15];
    const float* g2   = (const float*)d_in[16]; const float* b2  = (const float*)d_in[17];

    char* p = (char*)d_ws;
    auto take = [&](size_t bytes) { char* r = p; p += (bytes + 255) & ~(size_t)255; return r; };

    half_t* WqkvT = (half_t*)take((size_t)Lc * 3 * Hh * Hh * 2);   // 12 MB
    half_t* WaoT  = (half_t*)take((size_t)Lc * Hh * Hh * 2);       //  4 MB
    half_t* WiT   = (half_t*)take((size_t)Lc * Hh * FF * 2);       // 16 MB
    half_t* WoT   = (half_t*)take((size_t)Lc * FF * Hh * 2);       // 16 MB
    half_t* xb    = (half_t*)take((size_t)M * Hh * 2);             //  8 MB
    half_t* Qb    = (half_t*)take((size_t)M * Hh * 2);             //  8 MB
    half_t* Kb2   = (half_t*)take((size_t)M * Hh * 2);             //  8 MB
    half_t* Vtb   = (half_t*)take((size_t)M * Hh * 2);             //  8 MB
    (void)          take((size_t)M * Hh * 2);                      //  8 MB pad (h1 span)
    half_t* h1    = Qb;   // FFN hidden [M][FF] fp16 reuses Qb..pad (32 MB)
    float*  t0    = (float*)take((size_t)M * Hh * 4);              // 16 MB
    float*  x1f   = (float*)take((size_t)M * Hh * 4);              // 16 MB
    half_t* x1b   = (half_t*)take((size_t)M * Hh * 2);             //  8 MB

    dim3 tb(256);

    transpose_qkv<<<dim3(32, 32, Lc * 3), tb, 0, stream>>>(Wq, Wk, Wv, WqkvT);
    transpose_cast<<<dim3(32, 32, Lc), tb, 0, stream>>>(Wao, WaoT, Hh, Hh);
    transpose_cast<<<dim3(FF / 32, 32, Lc), tb, 0, stream>>>(Wi, WiT, Hh, FF);
    transpose_cast<<<dim3(32, FF / 32, Lc), tb, 0, stream>>>(Wo, WoT, FF, Hh);
    cast_f32_f16<<<dim3(M * Hh / 1024), tb, 0, stream>>>(hs, xb);

    const float* xres = hs;
    for (int l = 0; l < Lc; l++) {
        const half_t* WqkvTl = WqkvT + (size_t)l * 3 * Hh * Hh;
        const half_t* WaoTl  = WaoT  + (size_t)l * Hh * Hh;
        const half_t* WiTl   = WiT   + (size_t)l * Hh * FF;
        const half_t* WoTl   = WoT   + (size_t)l * FF * Hh;

        gemm_qkv<<<dim3(3072 / 128, M / 128), tb, 0, stream>>>(
            xb, WqkvTl, bq + l * Hh, bk + l * Hh, bv + l * Hh, Qb, Kb2, Vtb, M, Hh);

        flash_attn<<<dim3(S / 128, NH, Bb), tb, 0, stream>>>(Qb, Kb2, Vtb, mask, xb, S, Hh);

        gemm_bt64<<<dim3(Hh / 64, M / 128), tb, 0, stream>>>(
            xb, WaoTl, bao + l * Hh, xres, t0, M, Hh, Hh);
        layernorm_k<<<dim3(M), tb, 0, stream>>>(t0, g1 + l * Hh, b1 + l * Hh, x1f, x1b);

        gemm_bt<<<dim3(FF / 128, M / 128), tb, 0, stream>>>(
            x1b, WiTl, bi + l * FF, nullptr, h1, M, FF, Hh, MODE_GELU);
        gemm_bt64<<<dim3(Hh / 64, M / 128), tb, 0, stream>>>(
            h1, WoTl, bo + l * Hh, x1f, t0, M, Hh, FF);

        float* outf = (l == Lc - 1) ? (float*)d_out : x1f;
        layernorm_k<<<dim3(M), tb, 0, stream>>>(t0, g2 + l * Hh, b2 + l * Hh, outf, xb);
        xres = x1f;
    }
}

// Round 5
// 717.458 us; speedup vs baseline: 1.6649x; 1.0447x over previous
//
#include <hip/hip_runtime.h>

typedef _Float16 half_t;
typedef _Float16 half8  __attribute__((ext_vector_type(8)));
typedef _Float16 half4v __attribute__((ext_vector_type(4)));
typedef float    f32x4  __attribute__((ext_vector_type(4)));

#define AS1 __attribute__((address_space(1)))
#define AS3 __attribute__((address_space(3)))

#define MODE_H16  0   // store fp16
#define MODE_F32R 1   // store fp32 = acc + bias + residual
#define MODE_GELU 2   // store fp16 = gelu(acc + bias)

__device__ __forceinline__ f32x4 zero4() {
    f32x4 z; z[0] = 0.f; z[1] = 0.f; z[2] = 0.f; z[3] = 0.f; return z;
}

__device__ __forceinline__ half8 lds_frag(const half_t* p) {
    union { uint4 u; half8 h; } c;
    c.u = *(const uint4*)p;
    return c.h;
}

// fast tanh-GELU: v*sigmoid(1.59577(v+0.044715 v^3)); |err| ~3e-4
__device__ __forceinline__ float gelu_f(float v) {
    float t = v * v;
    float u = v * (1.595769122f + 0.0713548163f * t);
    return v / (1.f + __expf(-u));
}

// async global->LDS, 16B/lane; LDS dest is wave-uniform base + lane*16
__device__ __forceinline__ void gl_lds16(const half_t* g, half_t* l) {
    __builtin_amdgcn_global_load_lds(
        (AS1 unsigned int*)(unsigned long long)(const void*)g,
        (AS3 unsigned int*)l,
        16, 0, 0);
}

// ---------------------------------------------------------------------------
// BK=64 swizzled tiles: logical chunk c (8 els) of row r lives at phys chunk
// c^(r&7). Staging: lane -> row lane>>3, source chunk (lane&7)^((lane>>3)&7).
// ---------------------------------------------------------------------------

// C[M,N] = A[M,K] @ Bt[N,K]^T + bias, fused epilogues. 128x128 tile, BK=64.
__global__ __launch_bounds__(256) void gemm_bt(
    const half_t* __restrict__ A,
    const half_t* __restrict__ Bt,
    const float*  __restrict__ bias,
    const float*  __restrict__ res,
    void* __restrict__ out,
    int M, int N, int K, int mode)
{
    __shared__ __align__(16) half_t As[128 * 64];
    __shared__ __align__(16) half_t Bs[128 * 64];

    const int tid  = threadIdx.x;
    const int w    = tid >> 6, lane = tid & 63;
    const int m0   = blockIdx.y * 128, n0 = blockIdx.x * 128;
    const int g    = lane >> 4, ml = lane & 15, m7 = ml & 7;
    const int mo   = (w >> 1) * 64, no = (w & 1) * 64;
    const int r8   = lane >> 3;
    const int sck  = ((lane & 7) ^ (r8 & 7)) * 8;

    f32x4 acc[4][4];
#pragma unroll
    for (int i = 0; i < 4; i++)
#pragma unroll
        for (int j = 0; j < 4; j++) acc[i][j] = zero4();

    const half_t* Ag = A  + (size_t)m0 * K;
    const half_t* Bg = Bt + (size_t)n0 * K;

    for (int k0 = 0; k0 < K; k0 += 64) {
        __syncthreads();
#pragma unroll
        for (int i = 0; i < 4; i++) {
            int t = w * 4 + i;
            gl_lds16(Ag + (size_t)(t * 8 + r8) * K + k0 + sck, &As[t * 512]);
            gl_lds16(Bg + (size_t)(t * 8 + r8) * K + k0 + sck, &Bs[t * 512]);
        }
        __syncthreads();
#pragma unroll
        for (int kk = 0; kk < 2; kk++) {
            const int co = ((kk * 4 + g) ^ m7) * 8;
            half8 af[4], bf[4];
#pragma unroll
            for (int i = 0; i < 4; i++) af[i] = lds_frag(&As[(mo + i * 16 + ml) * 64 + co]);
#pragma unroll
            for (int j = 0; j < 4; j++) bf[j] = lds_frag(&Bs[(no + j * 16 + ml) * 64 + co]);
#pragma unroll
            for (int i = 0; i < 4; i++)
#pragma unroll
                for (int j = 0; j < 4; j++)
                    acc[i][j] = __builtin_amdgcn_mfma_f32_16x16x32_f16(af[i], bf[j], acc[i][j], 0, 0, 0);
        }
    }

    const int gm0 = m0 + mo, gn0 = n0 + no;
#pragma unroll
    for (int j = 0; j < 4; j++) {
        int col = gn0 + j * 16 + ml;
        float bv = bias[col];
#pragma unroll
        for (int i = 0; i < 4; i++) {
#pragma unroll
            for (int r = 0; r < 4; r++) {
                int row = gm0 + i * 16 + g * 4 + r;
                float v = acc[i][j][r] + bv;
                size_t idx = (size_t)row * N + col;
                if (mode == MODE_F32R) {
                    ((float*)out)[idx] = v + res[idx];
                } else if (mode == MODE_GELU) {
                    ((half_t*)out)[idx] = (half_t)gelu_f(v);
                } else {
                    ((half_t*)out)[idx] = (half_t)v;
                }
            }
        }
    }
}

// ---------------------------------------------------------------------------
// 128x64-tile GEMM for N=1024 cases. BK=64. MODE_F32R only.
// ---------------------------------------------------------------------------
__global__ __launch_bounds__(256) void gemm_bt64(
    const half_t* __restrict__ A,
    const half_t* __restrict__ Bt,
    const float*  __restrict__ bias,
    const float*  __restrict__ res,
    float* __restrict__ out,
    int M, int N, int K)
{
    __shared__ __align__(16) half_t As[128 * 64];
    __shared__ __align__(16) half_t Bs[64 * 64];

    const int tid  = threadIdx.x;
    const int w    = tid >> 6, lane = tid & 63;
    const int m0   = blockIdx.y * 128, n0 = blockIdx.x * 64;
    const int g    = lane >> 4, ml = lane & 15, m7 = ml & 7;
    const int mo   = w * 32;
    const int r8   = lane >> 3;
    const int sck  = ((lane & 7) ^ (r8 & 7)) * 8;

    f32x4 acc[2][4];
#pragma unroll
    for (int i = 0; i < 2; i++)
#pragma unroll
        for (int j = 0; j < 4; j++) acc[i][j] = zero4();

    const half_t* Ag = A  + (size_t)m0 * K;
    const half_t* Bg = Bt + (size_t)n0 * K;

    for (int k0 = 0; k0 < K; k0 += 64) {
        __syncthreads();
#pragma unroll
        for (int i = 0; i < 4; i++) {
            int t = w * 4 + i;
            gl_lds16(Ag + (size_t)(t * 8 + r8) * K + k0 + sck, &As[t * 512]);
        }
#pragma unroll
        for (int i = 0; i < 2; i++) {
            int t = w * 2 + i;
            gl_lds16(Bg + (size_t)(t * 8 + r8) * K + k0 + sck, &Bs[t * 512]);
        }
        __syncthreads();
#pragma unroll
        for (int kk = 0; kk < 2; kk++) {
            const int co = ((kk * 4 + g) ^ m7) * 8;
            half8 af[2], bf[4];
#pragma unroll
            for (int i = 0; i < 2; i++) af[i] = lds_frag(&As[(mo + i * 16 + ml) * 64 + co]);
#pragma unroll
            for (int j = 0; j < 4; j++) bf[j] = lds_frag(&Bs[(j * 16 + ml) * 64 + co]);
#pragma unroll
            for (int i = 0; i < 2; i++)
#pragma unroll
                for (int j = 0; j < 4; j++)
                    acc[i][j] = __builtin_amdgcn_mfma_f32_16x16x32_f16(af[i], bf[j], acc[i][j], 0, 0, 0);
        }
    }

    const int gm0 = m0 + mo;
#pragma unroll
    for (int j = 0; j < 4; j++) {
        int col = n0 + j * 16 + ml;
        float bv = bias[col];
#pragma unroll
        for (int i = 0; i < 2; i++) {
#pragma unroll
            for (int r = 0; r < 4; r++) {
                int row = gm0 + i * 16 + g * 4 + r;
                size_t idx = (size_t)row * N + col;
                out[idx] = acc[i][j][r] + bv + res[idx];
            }
        }
    }
}

// ---------------------------------------------------------------------------
// Fused QKV GEMM: N=3072 (Wq|Wk|Wv transposed, per-layer contiguous). BK=64.
// ---------------------------------------------------------------------------
__global__ __launch_bounds__(256) void gemm_qkv(
    const half_t* __restrict__ A,
    const half_t* __restrict__ Bt,
    const float*  __restrict__ bq,
    const float*  __restrict__ bk,
    const float*  __restrict__ bv,
    half_t* __restrict__ Qo, half_t* __restrict__ Ko, half_t* __restrict__ Vto,
    int M, int K)
{
    __shared__ __align__(16) half_t As[128 * 64];
    __shared__ __align__(16) half_t Bs[128 * 64];

    const int tid  = threadIdx.x;
    const int w    = tid >> 6, lane = tid & 63;
    const int m0   = blockIdx.y * 128, n0 = blockIdx.x * 128;
    const int g    = lane >> 4, ml = lane & 15, m7 = ml & 7;
    const int mo   = (w >> 1) * 64, no = (w & 1) * 64;
    const int r8   = lane >> 3;
    const int sck  = ((lane & 7) ^ (r8 & 7)) * 8;

    f32x4 acc[4][4];
#pragma unroll
    for (int i = 0; i < 4; i++)
#pragma unroll
        for (int j = 0; j < 4; j++) acc[i][j] = zero4();

    const half_t* Ag = A  + (size_t)m0 * K;
    const half_t* Bg = Bt + (size_t)n0 * K;

    for (int k0 = 0; k0 < K; k0 += 64) {
        __syncthreads();
#pragma unroll
        for (int i = 0; i < 4; i++) {
            int t = w * 4 + i;
            gl_lds16(Ag + (size_t)(t * 8 + r8) * K + k0 + sck, &As[t * 512]);
            gl_lds16(Bg + (size_t)(t * 8 + r8) * K + k0 + sck, &Bs[t * 512]);
        }
        __syncthreads();
#pragma unroll
        for (int kk = 0; kk < 2; kk++) {
            const int co = ((kk * 4 + g) ^ m7) * 8;
            half8 af[4], bf[4];
#pragma unroll
            for (int i = 0; i < 4; i++) af[i] = lds_frag(&As[(mo + i * 16 + ml) * 64 + co]);
#pragma unroll
            for (int j = 0; j < 4; j++) bf[j] = lds_frag(&Bs[(no + j * 16 + ml) * 64 + co]);
#pragma unroll
            for (int i = 0; i < 4; i++)
#pragma unroll
                for (int j = 0; j < 4; j++)
                    acc[i][j] = __builtin_amdgcn_mfma_f32_16x16x32_f16(af[i], bf[j], acc[i][j], 0, 0, 0);
        }
    }

    const int seg  = n0 >> 10;                  // block-uniform: 0=Q,1=K,2=V
    const int nloc = (n0 & 1023) + no;
    const float* bias = (seg == 0) ? bq : (seg == 1) ? bk : bv;
    const int gm0 = m0 + mo;

    if (seg < 2) {
        half_t* O = (seg == 0) ? Qo : Ko;
#pragma unroll
        for (int j = 0; j < 4; j++) {
            int col = nloc + j * 16 + ml;
            float bvv = bias[col];
#pragma unroll
            for (int i = 0; i < 4; i++)
#pragma unroll
                for (int r = 0; r < 4; r++)
                    O[(size_t)(gm0 + i * 16 + g * 4 + r) * 1024 + col] =
                        (half_t)(acc[i][j][r] + bvv);
        }
    } else {
#pragma unroll
        for (int j = 0; j < 4; j++) {
            int col = nloc + j * 16 + ml;
            float bvv = bias[col];
#pragma unroll
            for (int i = 0; i < 4; i++) {
                int rowb = gm0 + i * 16 + g * 4;
                int bb = rowb >> 11, sl = rowb & 2047;       // S=2048
                half4v v;
#pragma unroll
                for (int r = 0; r < 4; r++) v[r] = (half_t)(acc[i][j][r] + bvv);
                *(half4v*)&Vto[((size_t)bb * 1024 + col) * 2048 + sl] = v;
            }
        }
    }
}

// ---------------------------------------------------------------------------
// Flash attention v4: kv-split x2 (flash-decoding). Each block does one
// kv-half (S/2 positions) for 128 q rows; writes UNNORMALIZED O (fp16) and
// per-row (m,l) partials. grid (S/128, NH, B*2) = 1024 blocks = 4/CU.
// opart: [2][B*NH*S][64] fp16 ; mlpart: [2][B*NH*S] float2.
// ---------------------------------------------------------------------------
__global__ __launch_bounds__(256, 4) void flash_attn(
    const half_t* __restrict__ Q,
    const half_t* __restrict__ Kq,
    const half_t* __restrict__ Vt,
    const float*  __restrict__ mask,   // [B*S] additive
    half_t* __restrict__ opart,
    float2* __restrict__ mlpart,
    int S, int H)
{
    __shared__ __align__(16) half_t Ks[64 * 64];        // [kv][d]   (swizzled)
    __shared__ __align__(16) half_t Vs[64 * 64];        // [d][kv]   (swizzled)
    __shared__ __align__(16) half_t Ps[4 * 32 * 64];    // per-wave P[q][kv] (swizzled)

    const int qt = blockIdx.x, h = blockIdx.y, z = blockIdx.z;
    const int b = z >> 1, hf = z & 1;
    const int tid = threadIdx.x, w = tid >> 6, lane = tid & 63;
    const int g = lane >> 4, ml = lane & 15, m7 = ml & 7;
    const int NHloc = gridDim.y;
    const int BNHS = 2 * NHloc * S;   // B*NH*S (B=2)

    const int q0 = qt * 128 + w * 32;
    const half_t* Qg = Q  + ((size_t)(b * S + q0)) * H + h * 64;
    const half_t* Kg = Kq + ((size_t)b * S) * H + h * 64;
    const half_t* Vg = Vt + ((size_t)b * H + h * 64) * (size_t)S;
    const float*  mk = mask + (size_t)b * S;

    half8 qf[2][2];
#pragma unroll
    for (int qi = 0; qi < 2; qi++)
#pragma unroll
        for (int kk = 0; kk < 2; kk++)
            qf[qi][kk] = *(const half8*)(Qg + (size_t)(qi * 16 + ml) * H + kk * 32 + g * 8);

    float m_[2] = {-1e30f, -1e30f}, l_[2] = {0.f, 0.f};
    f32x4 o[2][4];
#pragma unroll
    for (int qi = 0; qi < 2; qi++)
#pragma unroll
        for (int df = 0; df < 4; df++) o[qi][df] = zero4();

    half_t* Pw = &Ps[w * 32 * 64];
    const int srow = tid >> 3;            // staging row (round t adds 32)
    const int sc   = tid & 7;             // phys 16B chunk within row

    const int kvbeg = hf * (S >> 1), kvend = kvbeg + (S >> 1);
    for (int kv0 = kvbeg; kv0 < kvend; kv0 += 64) {
        __syncthreads();
#pragma unroll
        for (int t = 0; t < 2; t++) {
            int row = t * 32 + srow;
            int ck  = sc ^ (row & 7);     // source chunk for phys chunk sc
            gl_lds16(Kg + (size_t)(kv0 + row) * H + ck * 8, &Ks[(t * 256 + w * 64) * 8]);
            gl_lds16(Vg + (size_t)row * S + kv0 + ck * 8,   &Vs[(t * 256 + w * 64) * 8]);
        }
        __syncthreads();

        f32x4 s[2][4];
#pragma unroll
        for (int kvf = 0; kvf < 4; kvf++) {
            half8 k0 = lds_frag(&Ks[(kvf * 16 + ml) * 64 + ((0 + g) ^ m7) * 8]);
            half8 k1 = lds_frag(&Ks[(kvf * 16 + ml) * 64 + ((4 + g) ^ m7) * 8]);
            s[0][kvf] = __builtin_amdgcn_mfma_f32_16x16x32_f16(k0, qf[0][0], zero4(), 0, 0, 0);
            s[0][kvf] = __builtin_amdgcn_mfma_f32_16x16x32_f16(k1, qf[0][1], s[0][kvf], 0, 0, 0);
            s[1][kvf] = __builtin_amdgcn_mfma_f32_16x16x32_f16(k0, qf[1][0], zero4(), 0, 0, 0);
            s[1][kvf] = __builtin_amdgcn_mfma_f32_16x16x32_f16(k1, qf[1][1], s[1][kvf], 0, 0, 0);
        }
#pragma unroll
        for (int kvf = 0; kvf < 4; kvf++) {
            float4 mv = *(const float4*)(mk + kv0 + kvf * 16 + g * 4);
#pragma unroll
            for (int qi = 0; qi < 2; qi++) {
                s[qi][kvf][0] = s[qi][kvf][0] * 0.125f + mv.x;
                s[qi][kvf][1] = s[qi][kvf][1] * 0.125f + mv.y;
                s[qi][kvf][2] = s[qi][kvf][2] * 0.125f + mv.z;
                s[qi][kvf][3] = s[qi][kvf][3] * 0.125f + mv.w;
            }
        }
        float alpha[2];
#pragma unroll
        for (int qi = 0; qi < 2; qi++) {
            float mx = -1e30f;
#pragma unroll
            for (int kvf = 0; kvf < 4; kvf++)
#pragma unroll
                for (int r = 0; r < 4; r++) mx = fmaxf(mx, s[qi][kvf][r]);
            mx = fmaxf(mx, __shfl_xor(mx, 16));
            mx = fmaxf(mx, __shfl_xor(mx, 32));
            float mnew = fmaxf(m_[qi], mx);
            alpha[qi]  = __expf(m_[qi] - mnew);
            m_[qi] = mnew;
            float ps = 0.f;
#pragma unroll
            for (int kvf = 0; kvf < 4; kvf++)
#pragma unroll
                for (int r = 0; r < 4; r++) {
                    float pv = __expf(s[qi][kvf][r] - mnew);
                    s[qi][kvf][r] = pv; ps += pv;
                }
            ps += __shfl_xor(ps, 16);
            ps += __shfl_xor(ps, 32);
            l_[qi] = l_[qi] * alpha[qi] + ps;
#pragma unroll
            for (int kvf = 0; kvf < 4; kvf++) {
                half4v pk;
#pragma unroll
                for (int r = 0; r < 4; r++) pk[r] = (half_t)s[qi][kvf][r];
                *(half4v*)(Pw + (qi * 16 + ml) * 64 +
                           (((kvf * 2 + (g >> 1)) ^ m7) * 8) + (g & 1) * 4) = pk;
            }
        }
#pragma unroll
        for (int qi = 0; qi < 2; qi++) {
#pragma unroll
            for (int r = 0; r < 4; r++) {
                float a = __shfl(alpha[qi], (lane & 48) + g * 4 + r);
#pragma unroll
                for (int df = 0; df < 4; df++) o[qi][df][r] *= a;
            }
        }
#pragma unroll
        for (int kk = 0; kk < 2; kk++) {
            half8 pa0 = lds_frag(&Pw[(ml)      * 64 + ((kk * 4 + g) ^ m7) * 8]);
            half8 pa1 = lds_frag(&Pw[(16 + ml) * 64 + ((kk * 4 + g) ^ m7) * 8]);
#pragma unroll
            for (int df = 0; df < 4; df++) {
                half8 vb = lds_frag(&Vs[(df * 16 + ml) * 64 + ((kk * 4 + g) ^ m7) * 8]);
                o[0][df] = __builtin_amdgcn_mfma_f32_16x16x32_f16(pa0, vb, o[0][df], 0, 0, 0);
                o[1][df] = __builtin_amdgcn_mfma_f32_16x16x32_f16(pa1, vb, o[1][df], 0, 0, 0);
            }
        }
    }

    // write partials: unnormalized o (fp16) + per-row (m,l)
    const size_t rowbase = (size_t)hf * BNHS + ((size_t)(b * NHloc + h)) * S + q0;
#pragma unroll
    for (int qi = 0; qi < 2; qi++) {
#pragma unroll
        for (int r = 0; r < 4; r++) {
            size_t ro = (rowbase + qi * 16 + g * 4 + r) * 64;
#pragma unroll
            for (int df = 0; df < 4; df++)
                opart[ro + df * 16 + ml] = (half_t)o[qi][df][r];
        }
    }
    if (g == 0) {
#pragma unroll
        for (int qi = 0; qi < 2; qi++)
            mlpart[rowbase + qi * 16 + ml] = make_float2(m_[qi], l_[qi]);
    }
}

// ---------------------------------------------------------------------------
// Merge the two kv-half partials -> ctx [B*S][H] fp16. One thread per 4 d.
// rows = B*NH*S = 65536; hardcoded S=2048, H=1024, NH=16, B=2.
// ---------------------------------------------------------------------------
__global__ __launch_bounds__(256) void flash_merge(
    const half_t* __restrict__ opart,
    const float2* __restrict__ mlpart,
    half_t* __restrict__ ctx)
{
    int gid = blockIdx.x * 256 + threadIdx.x;   // 65536*16
    int row = gid >> 4, dg = (gid & 15) * 4;
    float2 a = mlpart[row], c = mlpart[65536 + row];
    float m  = fmaxf(a.x, c.x);
    float w1 = __expf(a.x - m), w2 = __expf(c.x - m);
    float inv = 1.f / (w1 * a.y + w2 * c.y);
    half4v o1 = *(const half4v*)&opart[(size_t)row * 64 + dg];
    half4v o2 = *(const half4v*)&opart[(size_t)(65536 + row) * 64 + dg];
    int b = row >> 15, hq = row & 32767;
    int h = hq >> 11, q = hq & 2047;
    half4v o;
#pragma unroll
    for (int i = 0; i < 4; i++)
        o[i] = (half_t)((w1 * (float)o1[i] + w2 * (float)o2[i]) * inv);
    *(half4v*)&ctx[((size_t)(b * 2048 + q)) * 1024 + h * 64 + dg] = o;
}

// ---------------------------------------------------------------------------
// W[K][N] fp32 -> Wt[N][K] fp16 (32x32 tiles), batched over grid.z
// ---------------------------------------------------------------------------
__global__ __launch_bounds__(256) void transpose_cast(
    const float* __restrict__ W, half_t* __restrict__ Wt, int Kd, int Nd)
{
    __shared__ float tile[32][33];
    size_t zoff = (size_t)blockIdx.z * Kd * Nd;
    const float* Wz = W + zoff;
    half_t* Wtz = Wt + zoff;
    int n0 = blockIdx.x * 32, k0 = blockIdx.y * 32;
    int tx = threadIdx.x & 31, ty = threadIdx.x >> 5;
#pragma unroll
    for (int j = 0; j < 4; j++)
        tile[ty + j * 8][tx] = Wz[(size_t)(k0 + ty + j * 8) * Nd + n0 + tx];
    __syncthreads();
#pragma unroll
    for (int j = 0; j < 4; j++)
        Wtz[(size_t)(n0 + ty + j * 8) * Kd + k0 + tx] = (half_t)tile[tx][ty + j * 8];
}

// Q/K/V weights -> per-layer fused [l][3][H][H] transposed fp16
__global__ __launch_bounds__(256) void transpose_qkv(
    const float* __restrict__ Wq, const float* __restrict__ Wk,
    const float* __restrict__ Wv, half_t* __restrict__ WT)
{
    __shared__ float tile[32][33];
    int z = blockIdx.z, l = z / 3, which = z % 3;
    const float* W = ((which == 0) ? Wq : (which == 1) ? Wk : Wv) + (size_t)l * 1024 * 1024;
    half_t* D = WT + ((size_t)l * 3 + which) * 1024 * 1024;
    int n0 = blockIdx.x * 32, k0 = blockIdx.y * 32;
    int tx = threadIdx.x & 31, ty = threadIdx.x >> 5;
#pragma unroll
    for (int j = 0; j < 4; j++)
        tile[ty + j * 8][tx] = W[(size_t)(k0 + ty + j * 8) * 1024 + n0 + tx];
    __syncthreads();
#pragma unroll
    for (int j = 0; j < 4; j++)
        D[(size_t)(n0 + ty + j * 8) * 1024 + k0 + tx] = (half_t)tile[tx][ty + j * 8];
}

__global__ __launch_bounds__(256) void cast_f32_f16(
    const float* __restrict__ in, half_t* __restrict__ out)
{
    int i = blockIdx.x * 256 + threadIdx.x;
    float4 v = ((const float4*)in)[i];
    half4v o; o[0] = (half_t)v.x; o[1] = (half_t)v.y; o[2] = (half_t)v.z; o[3] = (half_t)v.w;
    *(half4v*)(out + (size_t)i * 4) = o;
}

// ---------------------------------------------------------------------------
// LayerNorm over H=1024; emits fp32 (residual path) + fp16 (next GEMM input)
// ---------------------------------------------------------------------------
__global__ __launch_bounds__(256) void layernorm_k(
    const float* __restrict__ in,
    const float* __restrict__ gam, const float* __restrict__ bet,
    float* __restrict__ outf, half_t* __restrict__ outh)
{
    int row = blockIdx.x, tid = threadIdx.x;
    const float4 v = ((const float4*)(in + (size_t)row * 1024))[tid];
    float s = v.x + v.y + v.z + v.w;
    float q = v.x * v.x + v.y * v.y + v.z * v.z + v.w * v.w;
    for (int off = 32; off; off >>= 1) { s += __shfl_down(s, off); q += __shfl_down(q, off); }
    __shared__ float ss[4], sq[4];
    int w = tid >> 6;
    if ((tid & 63) == 0) { ss[w] = s; sq[w] = q; }
    __syncthreads();
    float S_ = ss[0] + ss[1] + ss[2] + ss[3];
    float Q_ = sq[0] + sq[1] + sq[2] + sq[3];
    float mean = S_ * (1.f / 1024.f);
    float var  = Q_ * (1.f / 1024.f) - mean * mean;
    float rstd = rsqrtf(var + 1e-5f);
    float4 gm = ((const float4*)gam)[tid];
    float4 bt = ((const float4*)bet)[tid];
    float y0 = (v.x - mean) * rstd * gm.x + bt.x;
    float y1 = (v.y - mean) * rstd * gm.y + bt.y;
    float y2 = (v.z - mean) * rstd * gm.z + bt.z;
    float y3 = (v.w - mean) * rstd * gm.w + bt.w;
    ((float4*)(outf + (size_t)row * 1024))[tid] = make_float4(y0, y1, y2, y3);
    half4v oh; oh[0] = (half_t)y0; oh[1] = (half_t)y1; oh[2] = (half_t)y2; oh[3] = (half_t)y3;
    *(half4v*)(outh + (size_t)row * 1024 + tid * 4) = oh;
}

// ---------------------------------------------------------------------------
extern "C" void kernel_launch(void* const* d_in, const int* in_sizes, int n_in,
                              void* d_out, int out_size, void* d_ws, size_t ws_size,
                              hipStream_t stream)
{
    const int Lc = 2, Bb = 2, S = 2048, Hh = 1024, NH = 16, FF = 4096;
    const int M = Bb * S;  // 4096

    const float* hs   = (const float*)d_in[0];
    const float* mask = (const float*)d_in[1];
    const float* Wq   = (const float*)d_in[2];  const float* bq  = (const float*)d_in[3];
    const float* Wk   = (const float*)d_in[4];  const float* bk  = (const float*)d_in[5];
    const float* Wv   = (const float*)d_in[6];  const float* bv  = (const float*)d_in[7];
    const float* Wao  = (const float*)d_in[8];  const float* bao = (const float*)d_in[9];
    const float* g1   = (const float*)d_in[10]; const float* b1  = (const float*)d_in[11];
    const float* Wi   = (const float*)d_in[12]; const float* bi  = (const float*)d_in[13];
    const float* Wo   = (const float*)d_in[14]; const float* bo  = (const float*)d_in[15];
    const float* g2   = (const float*)d_in[16]; const float* b2  = (const float*)d_in[17];

    char* p = (char*)d_ws;
    auto take = [&](size_t bytes) { char* r = p; p += (bytes + 255) & ~(size_t)255; return r; };

    half_t* WqkvT = (half_t*)take((size_t)Lc * 3 * Hh * Hh * 2);   // 12 MB
    half_t* WaoT  = (half_t*)take((size_t)Lc * Hh * Hh * 2);       //  4 MB
    half_t* WiT   = (half_t*)take((size_t)Lc * Hh * FF * 2);       // 16 MB
    half_t* WoT   = (half_t*)take((size_t)Lc * FF * Hh * 2);       // 16 MB
    half_t* xb    = (half_t*)take((size_t)M * Hh * 2);             //  8 MB
    half_t* Qb    = (half_t*)take((size_t)M * Hh * 2);             //  8 MB
    half_t* Kb2   = (half_t*)take((size_t)M * Hh * 2);             //  8 MB
    half_t* Vtb   = (half_t*)take((size_t)M * Hh * 2);             //  8 MB
    (void)          take((size_t)M * Hh * 2);                      //  8 MB pad (h1 span)
    half_t* h1    = Qb;   // FFN hidden [M][FF] fp16 reuses Qb..pad (32 MB)
    float*  t0    = (float*)take((size_t)M * Hh * 4);              // 16 MB
    float*  x1f   = (float*)take((size_t)M * Hh * 4);              // 16 MB
    half_t* x1b   = (half_t*)take((size_t)M * Hh * 2);             //  8 MB

    // flash partials alias dead-at-attention buffers:
    half_t* opart  = (half_t*)t0;    // 2*65536*64*2 B = 16.78 MB == sizeof(t0)
    float2* mlpart = (float2*)x1b;   // 2*65536*8 B = 1 MB

    dim3 tb(256);

    transpose_qkv<<<dim3(32, 32, Lc * 3), tb, 0, stream>>>(Wq, Wk, Wv, WqkvT);
    transpose_cast<<<dim3(32, 32, Lc), tb, 0, stream>>>(Wao, WaoT, Hh, Hh);
    transpose_cast<<<dim3(FF / 32, 32, Lc), tb, 0, stream>>>(Wi, WiT, Hh, FF);
    transpose_cast<<<dim3(32, FF / 32, Lc), tb, 0, stream>>>(Wo, WoT, FF, Hh);
    cast_f32_f16<<<dim3(M * Hh / 1024), tb, 0, stream>>>(hs, xb);

    const float* xres = hs;
    for (int l = 0; l < Lc; l++) {
        const half_t* WqkvTl = WqkvT + (size_t)l * 3 * Hh * Hh;
        const half_t* WaoTl  = WaoT  + (size_t)l * Hh * Hh;
        const half_t* WiTl   = WiT   + (size_t)l * Hh * FF;
        const half_t* WoTl   = WoT   + (size_t)l * FF * Hh;

        gemm_qkv<<<dim3(3072 / 128, M / 128), tb, 0, stream>>>(
            xb, WqkvTl, bq + l * Hh, bk + l * Hh, bv + l * Hh, Qb, Kb2, Vtb, M, Hh);

        flash_attn<<<dim3(S / 128, NH, Bb * 2), tb, 0, stream>>>(
            Qb, Kb2, Vtb, mask, opart, mlpart, S, Hh);
        flash_merge<<<dim3(Bb * NH * S * 16 / 256), tb, 0, stream>>>(opart, mlpart, xb);

        gemm_bt64<<<dim3(Hh / 64, M / 128), tb, 0, stream>>>(
            xb, WaoTl, bao + l * Hh, xres, t0, M, Hh, Hh);
        layernorm_k<<<dim3(M), tb, 0, stream>>>(t0, g1 + l * Hh, b1 + l * Hh, x1f, x1b);

        gemm_bt<<<dim3(FF / 128, M / 128), tb, 0, stream>>>(
            x1b, WiTl, bi + l * FF, nullptr, h1, M, FF, Hh, MODE_GELU);
        gemm_bt64<<<dim3(Hh / 64, M / 128), tb, 0, stream>>>(
            h1, WoTl, bo + l * Hh, x1f, t0, M, Hh, FF);

        float* outf = (l == Lc - 1) ? (float*)d_out : x1f;
        layernorm_k<<<dim3(M), tb, 0, stream>>>(t0, g2 + l * Hh, b2 + l * Hh, outf, xb);
        xres = x1f;
    }
}